// Round 2
// baseline (57450.995 us; speedup 1.0000x reference)
//
#include <hip/hip_runtime.h>
#include <cstddef>

#define DEV static __device__ __forceinline__

DEV float b2f(unsigned short u){ unsigned int i=((unsigned int)u)<<16; float f; __builtin_memcpy(&f,&i,4); return f; }
DEV unsigned short f2b(float f){ unsigned int i; __builtin_memcpy(&i,&f,4); unsigned int r=(i+0x7fffu+((i>>16)&1u))>>16; return (unsigned short)r; }
DEV float sigf(float x){ return 1.f/(1.f+__expf(-x)); }
DEV float eluf(float x){ return x>0.f ? x : (__expf(x)-1.f); }
// dtype-adaptive load: flag f32 chosen at runtime by sniff kernel
DEV float gload(const void* p, long i, int f32){
  return f32 ? ((const float*)p)[i] : b2f(((const unsigned short*)p)[i]);
}

// ---------------------------------------------------------------------------
// Sniff input dtypes from raw bits (device-side, graph-capture safe).
// flags[0]=1 if float inputs are f32 (else bf16). flags[1]=1 if ints are i64.
// ---------------------------------------------------------------------------
__global__ __launch_bounds__(64) void sniff(const void* __restrict__ seqs,
                                            const void* __restrict__ seq_lens,
                                            int* __restrict__ flags)
{
  __shared__ int cnt;
  if (threadIdx.x==0) cnt=0;
  __syncthreads();
  const unsigned short* u = (const unsigned short*)seqs;
  int sane=0;
  for (int i=threadIdx.x;i<1024;i+=64){
    int e = (u[i]>>7)&0xFF;                 // bf16 exponent field
    if (e>=0x70 && e<=0x8F) sane++;         // |x| in [2^-15, 2^16]
  }
  atomicAdd(&cnt, sane);
  __syncthreads();
  if (threadIdx.x==0){
    flags[0] = (cnt < 820) ? 1 : 0;         // seqs~N(0,1): bf16 => ~1024 sane
    const int* s = (const int*)seq_lens;    // seq_lens in [512,1024]
    flags[1] = ((s[1]|s[3]|s[5]|s[7])==0) ? 1 : 0; // i64 => odd words zero
  }
}

// ---------------------------------------------------------------------------
// Prep: canonical bf16 transposed/concatenated weights in workspace.
// W0cat[k][g]: k<256 -> Wih0[g][k] (ctx part), k>=256 -> Whh0[g][k-256].
// Tail converts outW/inith/initc/qb0/qb1/outb to canonical bf16.
// ---------------------------------------------------------------------------
__global__ __launch_bounds__(256) void prep_transpose(
    const void* __restrict__ Wih0, const void* __restrict__ Whh0,
    const void* __restrict__ Wih1, const void* __restrict__ Whh1,
    const void* __restrict__ Wih2, const void* __restrict__ Whh2,
    const void* __restrict__ kW0,  const void* __restrict__ kW1,
    const void* __restrict__ vW0,  const void* __restrict__ vW1,
    const void* __restrict__ qW0,  const void* __restrict__ qW1,
    const void* __restrict__ bih0, const void* __restrict__ bhh0,
    const void* __restrict__ bih1, const void* __restrict__ bhh1,
    const void* __restrict__ bih2, const void* __restrict__ bhh2,
    const void* __restrict__ outW, const void* __restrict__ inith,
    const void* __restrict__ initc, const void* __restrict__ qb0,
    const void* __restrict__ qb1,  const void* __restrict__ outb,
    const int* __restrict__ flags,
    unsigned short* __restrict__ W0cat, unsigned short* __restrict__ W1cat,
    unsigned short* __restrict__ W2cat,
    unsigned short* __restrict__ kW0T, unsigned short* __restrict__ kW1T,
    unsigned short* __restrict__ vW0T, unsigned short* __restrict__ vW1T,
    unsigned short* __restrict__ qW0T, unsigned short* __restrict__ qW1T,
    float* __restrict__ bsum,
    unsigned short* __restrict__ outWc, unsigned short* __restrict__ inithc,
    unsigned short* __restrict__ initcc, unsigned short* __restrict__ qb0c,
    unsigned short* __restrict__ qb1c,  unsigned short* __restrict__ outbc)
{
  const int f32 = flags[0];
  int idx = blockIdx.x*256 + threadIdx.x;
  if (idx < 524288){ int k=idx>>10, g=idx&1023;
    W0cat[idx] = f2b((k<256)? gload(Wih0,(long)g*512+k,f32) : gload(Whh0,(long)g*256+(k-256),f32)); return; }
  idx -= 524288;
  if (idx < 524288){ int k=idx>>10, g=idx&1023;
    W1cat[idx] = f2b((k<256)? gload(Wih1,(long)g*256+k,f32) : gload(Whh1,(long)g*256+(k-256),f32)); return; }
  idx -= 524288;
  if (idx < 524288){ int k=idx>>10, g=idx&1023;
    W2cat[idx] = f2b((k<256)? gload(Wih2,(long)g*256+k,f32) : gload(Whh2,(long)g*256+(k-256),f32)); return; }
  idx -= 524288;
  if (idx < 262144){ int k=idx>>9, j=idx&511; kW0T[idx]=f2b(gload(kW0,(long)j*512+k,f32)); return; }
  idx -= 262144;
  if (idx < 32768){ int k=idx>>6, j=idx&63; kW1T[idx]=f2b(gload(kW1,(long)j*512+k,f32)); return; }
  idx -= 32768;
  if (idx < 131072){ int k=idx>>8, j=idx&255; vW0T[idx]=f2b(gload(vW0,(long)j*512+k,f32)); return; }
  idx -= 131072;
  if (idx < 65536){ int k=idx>>8, j=idx&255; vW1T[idx]=f2b(gload(vW1,(long)j*256+k,f32)); return; }
  idx -= 65536;
  if (idx < 65536){ int k=idx>>8, j=idx&255; qW0T[idx]=f2b(gload(qW0,(long)j*256+k,f32)); return; }
  idx -= 65536;
  if (idx < 16384){ int k=idx>>6, j=idx&63; qW1T[idx]=f2b(gload(qW1,(long)j*256+k,f32)); return; }
  idx -= 16384;
  if (idx < 3072){ int l=idx>>10, g=idx&1023;
    const void* bi = (l==0)?bih0:((l==1)?bih1:bih2);
    const void* bh = (l==0)?bhh0:((l==1)?bhh1:bhh2);
    bsum[idx] = gload(bi,g,f32)+gload(bh,g,f32); return; }
  idx -= 3072;
  if (idx < 17408){ outWc[idx]=f2b(gload(outW,idx,f32)); return; }
  idx -= 17408;
  if (idx < 768){ inithc[idx]=f2b(gload(inith,idx,f32)); return; }
  idx -= 768;
  if (idx < 768){ initcc[idx]=f2b(gload(initc,idx,f32)); return; }
  idx -= 768;
  if (idx < 256){ qb0c[idx]=f2b(gload(qb0,idx,f32)); return; }
  idx -= 256;
  if (idx < 64){ qb1c[idx]=f2b(gload(qb1,idx,f32)); return; }
  idx -= 64;
  if (idx < 34){ outbc[idx]=f2b(gload(outb,idx,f32)); return; }
}

// ge[v][g] = sum_k emb[v][k] * Wih0[g][256+k]   (x_t contribution to L0 gates)
__global__ __launch_bounds__(256) void prep_ge(
    const void* __restrict__ emb,
    const void* __restrict__ Wih0,
    const int* __restrict__ flags,
    float* __restrict__ ge)
{
  __shared__ float ev[256];
  const int f32 = flags[0];
  const int v = blockIdx.x, tid = threadIdx.x;
  ev[tid] = gload(emb,(long)v*256+tid,f32);
  __syncthreads();
  const int g0 = tid*4;
  #pragma unroll
  for (int j=0;j<4;j++){
    const int g = g0+j;
    float a = 0.f;
    #pragma unroll 4
    for (int k=0;k<256;k++) a += ev[k]*gload(Wih0,(long)g*512+256+k,f32);
    ge[(size_t)v*1024+g] = a;
  }
}

// ---------------------------------------------------------------------------
// key MLP: keyT[n][q][l], transposed so decode scores-loop reads contiguous l.
// ---------------------------------------------------------------------------
__global__ __launch_bounds__(256) void key_mlp(
    const void* __restrict__ seqs,
    const unsigned short* __restrict__ kW0T, const void* __restrict__ kb0,
    const unsigned short* __restrict__ kW1T, const void* __restrict__ kb1,
    const int* __restrict__ flags,
    unsigned short* __restrict__ keyT)
{
  __shared__ float Xt[16*512];          // 32 KB
  __shared__ unsigned short Hd[16*512]; // 16 KB
  const int f32 = flags[0];
  const int tid = threadIdx.x;
  const int R0 = blockIdx.x*16;
  for (int i=tid;i<8192;i+=256) Xt[i] = gload(seqs,(long)R0*512+i,f32);
  __syncthreads();
  { // layer 1: 512 hidden cols, 2 per thread
    const int j0 = 2*tid;
    float acc0[16], acc1[16];
    #pragma unroll
    for (int r=0;r<16;r++){ acc0[r]=0.f; acc1[r]=0.f; }
    for (int k=0;k<512;k++){
      ushort2 w = *reinterpret_cast<const ushort2*>(kW0T + (size_t)k*512 + j0);
      float w0=b2f(w.x), w1=b2f(w.y);
      #pragma unroll
      for (int r=0;r<16;r++){ float x = Xt[r*512+k]; acc0[r]+=x*w0; acc1[r]+=x*w1; }
    }
    float b0v=gload(kb0,j0,f32), b1v=gload(kb0,j0+1,f32);
    #pragma unroll
    for (int r=0;r<16;r++){
      Hd[r*512+j0]   = f2b(eluf(acc0[r]+b0v));
      Hd[r*512+j0+1] = f2b(eluf(acc1[r]+b1v));
    }
  }
  __syncthreads();
  { // layer 2: 64 out cols
    const int j = tid & 63;
    const int rbase = tid >> 6; // 0..3
    float acc[4] = {0.f,0.f,0.f,0.f};
    for (int k=0;k<512;k++){
      float w = b2f(kW1T[(size_t)k*64 + j]);
      #pragma unroll
      for (int m=0;m<4;m++) acc[m] += b2f(Hd[(rbase+4*m)*512 + k]) * w;
    }
    float bv = gload(kb1,j,f32);
    #pragma unroll
    for (int m=0;m<4;m++){
      int R = R0 + rbase + 4*m;
      int l = R >> 6, n = R & 63;
      keyT[((size_t)(n*64 + j))*1024 + l] = f2b(acc[m]+bv);
    }
  }
}

// ---------------------------------------------------------------------------
// value MLP: value[n][l][h]
// ---------------------------------------------------------------------------
__global__ __launch_bounds__(256) void value_mlp(
    const void* __restrict__ seqs,
    const unsigned short* __restrict__ vW0T, const void* __restrict__ vb0,
    const unsigned short* __restrict__ vW1T, const void* __restrict__ vb1,
    const int* __restrict__ flags,
    unsigned short* __restrict__ value)
{
  __shared__ float Xt[16*512]; // 32 KB
  __shared__ float Hd[16*256]; // 16 KB
  const int f32 = flags[0];
  const int tid = threadIdx.x;
  const int R0 = blockIdx.x*16;
  for (int i=tid;i<8192;i+=256) Xt[i] = gload(seqs,(long)R0*512+i,f32);
  __syncthreads();
  { // layer 1: 256 hidden cols; thread: 2 cols x 8 rows
    const int j0 = 2*(tid & 127);
    const int rh = tid >> 7; // 0..1
    float acc0[8], acc1[8];
    #pragma unroll
    for (int r=0;r<8;r++){ acc0[r]=0.f; acc1[r]=0.f; }
    for (int k=0;k<512;k++){
      ushort2 w = *reinterpret_cast<const ushort2*>(vW0T + (size_t)k*256 + j0);
      float w0=b2f(w.x), w1=b2f(w.y);
      #pragma unroll
      for (int r=0;r<8;r++){ float x = Xt[(rh*8+r)*512+k]; acc0[r]+=x*w0; acc1[r]+=x*w1; }
    }
    float b0v=gload(vb0,j0,f32), b1v=gload(vb0,j0+1,f32);
    #pragma unroll
    for (int r=0;r<8;r++){
      Hd[(rh*8+r)*256+j0]   = eluf(acc0[r]+b0v);
      Hd[(rh*8+r)*256+j0+1] = eluf(acc1[r]+b1v);
    }
  }
  __syncthreads();
  { // layer 2: 256 out cols, thread j = tid over all 16 rows
    const int j = tid;
    float acc[16];
    #pragma unroll
    for (int r=0;r<16;r++) acc[r]=0.f;
    for (int k=0;k<256;k++){
      float w = b2f(vW1T[(size_t)k*256 + j]);
      #pragma unroll
      for (int r=0;r<16;r++) acc[r] += Hd[r*256+k]*w;
    }
    float bv = gload(vb1,j,f32);
    #pragma unroll
    for (int r=0;r<16;r++){
      int R = R0 + r; int l = R>>6, n = R&63;
      value[((size_t)n*1024 + l)*256 + j] = f2b(acc[r]+bv);
    }
  }
}

// ---------------------------------------------------------------------------
// Decode: one block per batch element n, 256 threads, all T=256 steps.
// Recurrence is per-n independent -> zero inter-block sync.
// ---------------------------------------------------------------------------
__global__ __launch_bounds__(256) void speller(
    const unsigned short* __restrict__ keyT,
    const unsigned short* __restrict__ value,
    const unsigned short* __restrict__ W0cat,
    const unsigned short* __restrict__ W1cat,
    const unsigned short* __restrict__ W2cat,
    const unsigned short* __restrict__ qW0T,
    const unsigned short* __restrict__ qW1T,
    const float* __restrict__ bsum,
    const float* __restrict__ ge,
    const unsigned short* __restrict__ inithc,
    const unsigned short* __restrict__ initcc,
    const unsigned short* __restrict__ qb0c,
    const unsigned short* __restrict__ qb1c,
    const unsigned short* __restrict__ outWc,
    const unsigned short* __restrict__ outbc,
    const int* __restrict__ labels,
    const int* __restrict__ seq_lens,
    const int* __restrict__ flags,
    void* __restrict__ out)
{
  __shared__ float ctx[256];
  __shared__ float h[3][256];
  __shared__ float c[3][256];
  __shared__ float gates[1024];
  __shared__ float sc[1024];
  __shared__ float xq[256];
  __shared__ float qv[64];
  __shared__ float red[256];
  const int tid = threadIdx.x;
  const int n = blockIdx.x;
  const int f32 = flags[0];
  const int i64 = flags[1];
  const int slen = i64 ? seq_lens[2*n] : seq_lens[n];

  #pragma unroll
  for (int l=0;l<3;l++){
    h[l][tid] = b2f(inithc[l*256+tid]);
    c[l][tid] = b2f(initcc[l*256+tid]);
  }
  __syncthreads();

  const unsigned short* kbase = keyT  + (size_t)n*64*1024;
  const unsigned short* vbase = value + (size_t)n*1024*256;

  auto lstm_layer = [&](const float* in0, const float* in1,
                        const unsigned short* Wcat, const float* bs,
                        const float* geRow, float* hl, float* cl){
    const int g0 = tid*4;
    float a0=bs[g0], a1=bs[g0+1], a2=bs[g0+2], a3=bs[g0+3];
    if (geRow){ a0+=geRow[g0]; a1+=geRow[g0+1]; a2+=geRow[g0+2]; a3+=geRow[g0+3]; }
    const unsigned short* wp = Wcat + g0;
    #pragma unroll 4
    for (int k=0;k<256;k++){
      float x = in0[k];
      ushort4 w = *reinterpret_cast<const ushort4*>(wp + (size_t)k*1024);
      a0 += x*b2f(w.x); a1 += x*b2f(w.y); a2 += x*b2f(w.z); a3 += x*b2f(w.w);
    }
    const unsigned short* wp2 = wp + 256*1024;
    #pragma unroll 4
    for (int k=0;k<256;k++){
      float x = in1[k];
      ushort4 w = *reinterpret_cast<const ushort4*>(wp2 + (size_t)k*1024);
      a0 += x*b2f(w.x); a1 += x*b2f(w.y); a2 += x*b2f(w.z); a3 += x*b2f(w.w);
    }
    gates[g0]=a0; gates[g0+1]=a1; gates[g0+2]=a2; gates[g0+3]=a3;
    __syncthreads();
    float gi=gates[tid], gf=gates[256+tid], gg=gates[512+tid], go=gates[768+tid];
    float cc = sigf(gf)*cl[tid] + sigf(gi)*tanhf(gg);
    float hh = sigf(go)*tanhf(cc);
    cl[tid]=cc; hl[tid]=hh;
    __syncthreads();
  };

  auto attn = [&](){
    { // q hidden = ELU(h2 @ qW0.T + qb0)
      float a = b2f(qb0c[tid]);
      const unsigned short* wp = qW0T + tid;
      #pragma unroll 4
      for (int k=0;k<256;k++) a += h[2][k]*b2f(wp[k*256]);
      xq[tid] = eluf(a);
    }
    __syncthreads();
    if (tid < 64){ // q = hidden @ qW1.T + qb1
      float a = b2f(qb1c[tid]);
      const unsigned short* wp = qW1T + tid;
      #pragma unroll 4
      for (int k=0;k<256;k++) a += xq[k]*b2f(wp[k*64]);
      qv[tid] = a;
    }
    __syncthreads();
    // scores s[l] = key[n,l,:] . q
    const int l0 = tid*4;
    float s0=0.f,s1=0.f,s2=0.f,s3=0.f;
    #pragma unroll 4
    for (int q=0;q<64;q++){
      float qq = qv[q];
      ushort4 w = *reinterpret_cast<const ushort4*>(kbase + (size_t)q*1024 + l0);
      s0 += qq*b2f(w.x); s1 += qq*b2f(w.y); s2 += qq*b2f(w.z); s3 += qq*b2f(w.w);
    }
    float m = fmaxf(fmaxf(s0,s1),fmaxf(s2,s3));
    red[tid]=m; __syncthreads();
    for (int s=128;s>=1;s>>=1){ if (tid<s) red[tid]=fmaxf(red[tid],red[tid+s]); __syncthreads(); }
    const float M = red[0];
    __syncthreads();
    float e0 = (l0+0<slen)? __expf(s0-M):0.f;
    float e1 = (l0+1<slen)? __expf(s1-M):0.f;
    float e2 = (l0+2<slen)? __expf(s2-M):0.f;
    float e3 = (l0+3<slen)? __expf(s3-M):0.f;
    sc[l0]=e0; sc[l0+1]=e1; sc[l0+2]=e2; sc[l0+3]=e3;
    red[tid]=e0+e1+e2+e3; __syncthreads();
    for (int s=128;s>=1;s>>=1){ if (tid<s) red[tid]+=red[tid+s]; __syncthreads(); }
    const float invS = 1.f/red[0];
    float a = 0.f;
    const unsigned short* vp = vbase + tid;
    #pragma unroll 8
    for (int l=0;l<slen;l++) a += sc[l]*b2f(vp[(size_t)l*256]);
    ctx[tid] = a*invS;
    __syncthreads();
  };

  attn(); // initial prev_ctx from initial h[2]

  for (int t=0;t<256;t++){
    const int lab = i64 ? labels[2*(t*64+n)] : labels[t*64+n];
    lstm_layer(ctx,  h[0], W0cat, bsum,      ge + (size_t)lab*1024, h[0], c[0]);
    lstm_layer(h[0], h[1], W1cat, bsum+1024, nullptr,               h[1], c[1]);
    lstm_layer(h[1], h[2], W2cat, bsum+2048, nullptr,               h[2], c[2]);
    attn();
    if (tid < 34){
      float a = b2f(outbc[tid]);
      const unsigned short* wr = outWc + (size_t)tid*512;
      #pragma unroll 4
      for (int k=0;k<256;k++) a += ctx[k]*b2f(wr[k]);
      #pragma unroll 4
      for (int k=0;k<256;k++) a += h[2][k]*b2f(wr[256+k]);
      size_t oi = ((size_t)t*64+n)*34 + tid;
      if (f32) ((float*)out)[oi] = a;
      else     ((unsigned short*)out)[oi] = f2b(a);
    }
    // next write to ctx/h[2] is >=2 __syncthreads away -> no trailing sync
  }
}

extern "C" void kernel_launch(void* const* d_in, const int* in_sizes, int n_in,
                              void* d_out, int out_size, void* d_ws, size_t ws_size,
                              hipStream_t stream) {
  const void* seqs  = d_in[0];
  const int* seq_lens = (const int*)d_in[1];
  const int* labels   = (const int*)d_in[2];
  const void* emb   = d_in[3];
  const void* inith = d_in[4];
  const void* initc = d_in[5];
  const void* Wih0 = d_in[6];  const void* Whh0 = d_in[7];
  const void* bih0 = d_in[8];  const void* bhh0 = d_in[9];
  const void* Wih1 = d_in[10]; const void* Whh1 = d_in[11];
  const void* bih1 = d_in[12]; const void* bhh1 = d_in[13];
  const void* Wih2 = d_in[14]; const void* Whh2 = d_in[15];
  const void* bih2 = d_in[16]; const void* bhh2 = d_in[17];
  const void* qW0 = d_in[18];  const void* qb0 = d_in[19];
  const void* qW1 = d_in[20];  const void* qb1 = d_in[21];
  const void* kW0 = d_in[22];  const void* kb0 = d_in[23];
  const void* kW1 = d_in[24];  const void* kb1 = d_in[25];
  const void* vW0 = d_in[26];  const void* vb0 = d_in[27];
  const void* vW1 = d_in[28];  const void* vb1 = d_in[29];
  const void* outW = d_in[30]; const void* outb = d_in[31];

  char* ws = (char*)d_ws;
  unsigned short* keyT  = (unsigned short*)(ws);             //  8,388,608 B  [64][64][1024]
  unsigned short* value = (unsigned short*)(ws + 8388608);   // 33,554,432 B  [64][1024][256]
  unsigned short* W0cat = (unsigned short*)(ws + 41943040);  //  1,048,576 B  [512][1024]
  unsigned short* W1cat = (unsigned short*)(ws + 42991616);
  unsigned short* W2cat = (unsigned short*)(ws + 44040192);
  unsigned short* kW0T  = (unsigned short*)(ws + 45088768);  //    524,288 B
  unsigned short* kW1T  = (unsigned short*)(ws + 45613056);  //     65,536 B
  unsigned short* vW0T  = (unsigned short*)(ws + 45678592);  //    262,144 B
  unsigned short* vW1T  = (unsigned short*)(ws + 45940736);  //    131,072 B
  unsigned short* qW0T  = (unsigned short*)(ws + 46071808);  //    131,072 B
  unsigned short* qW1T  = (unsigned short*)(ws + 46202880);  //     32,768 B
  float*          bsum  = (float*)(ws + 46235648);           //     12,288 B
  float*          ge    = (float*)(ws + 46247936);           //    139,264 B  [34][1024]
  unsigned short* outWc = (unsigned short*)(ws + 46387200);  //     34,816 B  [34][512]
  unsigned short* inithc= (unsigned short*)(ws + 46422016);  //      1,536 B
  unsigned short* initcc= (unsigned short*)(ws + 46423552);  //      1,536 B
  unsigned short* qb0c  = (unsigned short*)(ws + 46425088);  //        512 B
  unsigned short* qb1c  = (unsigned short*)(ws + 46425600);  //        128 B
  unsigned short* outbc = (unsigned short*)(ws + 46425728);  //        128 B
  int*            flags = (int*)(ws + 46425856);             //          8 B

  sniff<<<dim3(1), dim3(64), 0, stream>>>(seqs, seq_lens, flags);
  prep_transpose<<<dim3(8472), dim3(256), 0, stream>>>(
      Wih0,Whh0,Wih1,Whh1,Wih2,Whh2, kW0,kW1,vW0,vW1,qW0,qW1,
      bih0,bhh0,bih1,bhh1,bih2,bhh2,
      outW,inith,initc,qb0,qb1,outb, flags,
      W0cat,W1cat,W2cat,kW0T,kW1T,vW0T,vW1T,qW0T,qW1T,bsum,
      outWc,inithc,initcc,qb0c,qb1c,outbc);
  prep_ge<<<dim3(34), dim3(256), 0, stream>>>(emb, Wih0, flags, ge);
  key_mlp<<<dim3(4096), dim3(256), 0, stream>>>(seqs, kW0T, kb0, kW1T, kb1, flags, keyT);
  value_mlp<<<dim3(4096), dim3(256), 0, stream>>>(seqs, vW0T, vb0, vW1T, vb1, flags, value);
  speller<<<dim3(64), dim3(256), 0, stream>>>(
      keyT, value, W0cat, W1cat, W2cat, qW0T, qW1T, bsum, ge,
      inithc, initcc, qb0c, qb1c, outWc, outbc, labels, seq_lens, flags,
      d_out);
}

// Round 3
// 23387.617 us; speedup vs baseline: 2.4565x; 2.4565x over previous
//
#include <hip/hip_runtime.h>
#include <cstddef>

#define DEV static __device__ __forceinline__

DEV float b2f(unsigned short u){ unsigned int i=((unsigned int)u)<<16; float f; __builtin_memcpy(&f,&i,4); return f; }
DEV unsigned short f2b(float f){ unsigned int i; __builtin_memcpy(&i,&f,4); unsigned int r=(i+0x7fffu+((i>>16)&1u))>>16; return (unsigned short)r; }
DEV float sigf(float x){ return 1.f/(1.f+__expf(-x)); }
DEV float eluf(float x){ return x>0.f ? x : (__expf(x)-1.f); }
DEV float gload(const void* p, long i, int f32){
  return f32 ? ((const float*)p)[i] : b2f(((const unsigned short*)p)[i]);
}

// ---------------------------------------------------------------------------
// Sniff input dtypes from raw bits. flags[0]=1 if floats are f32, flags[1]=1
// if ints are i64.
// ---------------------------------------------------------------------------
__global__ __launch_bounds__(64) void sniff(const void* __restrict__ seqs,
                                            const void* __restrict__ seq_lens,
                                            int* __restrict__ flags)
{
  __shared__ int cnt;
  if (threadIdx.x==0) cnt=0;
  __syncthreads();
  const unsigned short* u = (const unsigned short*)seqs;
  int sane=0;
  for (int i=threadIdx.x;i<1024;i+=64){
    int e = (u[i]>>7)&0xFF;
    if (e>=0x70 && e<=0x8F) sane++;
  }
  atomicAdd(&cnt, sane);
  __syncthreads();
  if (threadIdx.x==0){
    flags[0] = (cnt < 820) ? 1 : 0;
    const int* s = (const int*)seq_lens;
    flags[1] = ((s[1]|s[3]|s[5]|s[7])==0) ? 1 : 0;
  }
}

// ---------------------------------------------------------------------------
// Prep: canonical bf16 weights in part-sliced layouts.
// Wl[l][part][k][gi]: gi in [0,256): type=gi>>6, jj=gi&63, global gate
// g = type*256 + part*64 + jj.  k<256 -> ih weight (ctx/h_in), k>=256 -> hh.
// ---------------------------------------------------------------------------
__global__ __launch_bounds__(256) void prep_transpose(
    const void* __restrict__ Wih0, const void* __restrict__ Whh0,
    const void* __restrict__ Wih1, const void* __restrict__ Whh1,
    const void* __restrict__ Wih2, const void* __restrict__ Whh2,
    const void* __restrict__ kW0,  const void* __restrict__ kW1,
    const void* __restrict__ vW0,  const void* __restrict__ vW1,
    const void* __restrict__ qW0,  const void* __restrict__ qW1,
    const void* __restrict__ bih0, const void* __restrict__ bhh0,
    const void* __restrict__ bih1, const void* __restrict__ bhh1,
    const void* __restrict__ bih2, const void* __restrict__ bhh2,
    const void* __restrict__ outW, const void* __restrict__ inith,
    const void* __restrict__ initc, const void* __restrict__ qb0,
    const void* __restrict__ qb1,  const void* __restrict__ outb,
    const int* __restrict__ flags,
    unsigned short* __restrict__ Wl0, unsigned short* __restrict__ Wl1,
    unsigned short* __restrict__ Wl2,
    unsigned short* __restrict__ kW0T, unsigned short* __restrict__ kW1T,
    unsigned short* __restrict__ vW0T, unsigned short* __restrict__ vW1T,
    unsigned short* __restrict__ qW0T, unsigned short* __restrict__ qW1T,
    float* __restrict__ bsum,
    unsigned short* __restrict__ outWc, unsigned short* __restrict__ inithc,
    unsigned short* __restrict__ initcc, unsigned short* __restrict__ qb0c,
    unsigned short* __restrict__ qb1c,  unsigned short* __restrict__ outbc)
{
  const int f32 = flags[0];
  int idx = blockIdx.x*256 + threadIdx.x;
  if (idx < 524288){ int r=idx&131071, k=r>>8, gi=r&255;
    int g = ((gi>>6)<<8) + ((idx>>17)<<6) + (gi&63);
    Wl0[idx] = f2b((k<256)? gload(Wih0,(long)g*512+k,f32) : gload(Whh0,(long)g*256+(k-256),f32)); return; }
  idx -= 524288;
  if (idx < 524288){ int r=idx&131071, k=r>>8, gi=r&255;
    int g = ((gi>>6)<<8) + ((idx>>17)<<6) + (gi&63);
    Wl1[idx] = f2b((k<256)? gload(Wih1,(long)g*256+k,f32) : gload(Whh1,(long)g*256+(k-256),f32)); return; }
  idx -= 524288;
  if (idx < 524288){ int r=idx&131071, k=r>>8, gi=r&255;
    int g = ((gi>>6)<<8) + ((idx>>17)<<6) + (gi&63);
    Wl2[idx] = f2b((k<256)? gload(Wih2,(long)g*256+k,f32) : gload(Whh2,(long)g*256+(k-256),f32)); return; }
  idx -= 524288;
  if (idx < 262144){ int k=idx>>9, j=idx&511; kW0T[idx]=f2b(gload(kW0,(long)j*512+k,f32)); return; }
  idx -= 262144;
  if (idx < 32768){ int k=idx>>6, j=idx&63; kW1T[idx]=f2b(gload(kW1,(long)j*512+k,f32)); return; }
  idx -= 32768;
  if (idx < 131072){ int k=idx>>8, j=idx&255; vW0T[idx]=f2b(gload(vW0,(long)j*512+k,f32)); return; }
  idx -= 131072;
  if (idx < 65536){ int k=idx>>8, j=idx&255; vW1T[idx]=f2b(gload(vW1,(long)j*256+k,f32)); return; }
  idx -= 65536;
  if (idx < 65536){ int k=idx>>8, j=idx&255; qW0T[idx]=f2b(gload(qW0,(long)j*256+k,f32)); return; }
  idx -= 65536;
  if (idx < 16384){ int k=idx>>6, j=idx&63; qW1T[idx]=f2b(gload(qW1,(long)j*256+k,f32)); return; }
  idx -= 16384;
  if (idx < 3072){ int l=idx>>10, r=idx&1023, pp=r>>8, gi=r&255;
    int g = ((gi>>6)<<8) + (pp<<6) + (gi&63);
    const void* bi = (l==0)?bih0:((l==1)?bih1:bih2);
    const void* bh = (l==0)?bhh0:((l==1)?bhh1:bhh2);
    bsum[idx] = gload(bi,g,f32)+gload(bh,g,f32); return; }
  idx -= 3072;
  if (idx < 17408){ outWc[idx]=f2b(gload(outW,idx,f32)); return; }
  idx -= 17408;
  if (idx < 768){ inithc[idx]=f2b(gload(inith,idx,f32)); return; }
  idx -= 768;
  if (idx < 768){ initcc[idx]=f2b(gload(initc,idx,f32)); return; }
  idx -= 768;
  if (idx < 256){ qb0c[idx]=f2b(gload(qb0,idx,f32)); return; }
  idx -= 256;
  if (idx < 64){ qb1c[idx]=f2b(gload(qb1,idx,f32)); return; }
  idx -= 64;
  if (idx < 34){ outbc[idx]=f2b(gload(outb,idx,f32)); return; }
}

// gep[part][v][gi] = sum_k emb[v][k] * Wih0[g(part,gi)][256+k]
__global__ __launch_bounds__(256) void prep_ge(
    const void* __restrict__ emb,
    const void* __restrict__ Wih0,
    const int* __restrict__ flags,
    float* __restrict__ gep)
{
  __shared__ float ev[256];
  const int f32 = flags[0];
  const int v = blockIdx.x, tid = threadIdx.x;
  ev[tid] = gload(emb,(long)v*256+tid,f32);
  __syncthreads();
  #pragma unroll
  for (int j=0;j<4;j++){
    const int g = tid*4+j;
    float a = 0.f;
    #pragma unroll 4
    for (int k=0;k<256;k++) a += ev[k]*gload(Wih0,(long)g*512+256+k,f32);
    int pp = (g>>6)&3, gi = ((g>>8)<<6)|(g&63);
    gep[((size_t)pp*34+v)*256+gi] = a;
  }
}

// ---------------------------------------------------------------------------
// key MLP: keyT[n][q][l]
// ---------------------------------------------------------------------------
__global__ __launch_bounds__(256) void key_mlp(
    const void* __restrict__ seqs,
    const unsigned short* __restrict__ kW0T, const void* __restrict__ kb0,
    const unsigned short* __restrict__ kW1T, const void* __restrict__ kb1,
    const int* __restrict__ flags,
    unsigned short* __restrict__ keyT)
{
  __shared__ float Xt[16*512];
  __shared__ unsigned short Hd[16*512];
  const int f32 = flags[0];
  const int tid = threadIdx.x;
  const int R0 = blockIdx.x*16;
  for (int i=tid;i<8192;i+=256) Xt[i] = gload(seqs,(long)R0*512+i,f32);
  __syncthreads();
  {
    const int j0 = 2*tid;
    float acc0[16], acc1[16];
    #pragma unroll
    for (int r=0;r<16;r++){ acc0[r]=0.f; acc1[r]=0.f; }
    for (int k=0;k<512;k++){
      ushort2 w = *reinterpret_cast<const ushort2*>(kW0T + (size_t)k*512 + j0);
      float w0=b2f(w.x), w1=b2f(w.y);
      #pragma unroll
      for (int r=0;r<16;r++){ float x = Xt[r*512+k]; acc0[r]+=x*w0; acc1[r]+=x*w1; }
    }
    float b0v=gload(kb0,j0,f32), b1v=gload(kb0,j0+1,f32);
    #pragma unroll
    for (int r=0;r<16;r++){
      Hd[r*512+j0]   = f2b(eluf(acc0[r]+b0v));
      Hd[r*512+j0+1] = f2b(eluf(acc1[r]+b1v));
    }
  }
  __syncthreads();
  {
    const int j = tid & 63;
    const int rbase = tid >> 6;
    float acc[4] = {0.f,0.f,0.f,0.f};
    for (int k=0;k<512;k++){
      float w = b2f(kW1T[(size_t)k*64 + j]);
      #pragma unroll
      for (int m=0;m<4;m++) acc[m] += b2f(Hd[(rbase+4*m)*512 + k]) * w;
    }
    float bv = gload(kb1,j,f32);
    #pragma unroll
    for (int m=0;m<4;m++){
      int R = R0 + rbase + 4*m;
      int l = R >> 6, n = R & 63;
      keyT[((size_t)(n*64 + j))*1024 + l] = f2b(acc[m]+bv);
    }
  }
}

// ---------------------------------------------------------------------------
// value MLP: value[n][l][h]
// ---------------------------------------------------------------------------
__global__ __launch_bounds__(256) void value_mlp(
    const void* __restrict__ seqs,
    const unsigned short* __restrict__ vW0T, const void* __restrict__ vb0,
    const unsigned short* __restrict__ vW1T, const void* __restrict__ vb1,
    const int* __restrict__ flags,
    unsigned short* __restrict__ value)
{
  __shared__ float Xt[16*512];
  __shared__ float Hd[16*256];
  const int f32 = flags[0];
  const int tid = threadIdx.x;
  const int R0 = blockIdx.x*16;
  for (int i=tid;i<8192;i+=256) Xt[i] = gload(seqs,(long)R0*512+i,f32);
  __syncthreads();
  {
    const int j0 = 2*(tid & 127);
    const int rh = tid >> 7;
    float acc0[8], acc1[8];
    #pragma unroll
    for (int r=0;r<8;r++){ acc0[r]=0.f; acc1[r]=0.f; }
    for (int k=0;k<512;k++){
      ushort2 w = *reinterpret_cast<const ushort2*>(vW0T + (size_t)k*256 + j0);
      float w0=b2f(w.x), w1=b2f(w.y);
      #pragma unroll
      for (int r=0;r<8;r++){ float x = Xt[(rh*8+r)*512+k]; acc0[r]+=x*w0; acc1[r]+=x*w1; }
    }
    float b0v=gload(vb0,j0,f32), b1v=gload(vb0,j0+1,f32);
    #pragma unroll
    for (int r=0;r<8;r++){
      Hd[(rh*8+r)*256+j0]   = eluf(acc0[r]+b0v);
      Hd[(rh*8+r)*256+j0+1] = eluf(acc1[r]+b1v);
    }
  }
  __syncthreads();
  {
    const int j = tid;
    float acc[16];
    #pragma unroll
    for (int r=0;r<16;r++) acc[r]=0.f;
    for (int k=0;k<256;k++){
      float w = b2f(vW1T[(size_t)k*256 + j]);
      #pragma unroll
      for (int r=0;r<16;r++) acc[r] += Hd[r*256+k]*w;
    }
    float bv = gload(vb1,j,f32);
    #pragma unroll
    for (int r=0;r<16;r++){
      int R = R0 + r; int l = R>>6, n = R&63;
      value[((size_t)n*1024 + l)*256 + j] = f2b(acc[r]+bv);
    }
  }
}

__global__ __launch_bounds__(256) void zero_sync(int* __restrict__ f){
  f[threadIdx.x] = 0;
}

// ---------------------------------------------------------------------------
// Decode: 256 blocks x 512 threads. Block = (part p, batch n): bid = p*64+n,
// so the 4 parts of n are 64 apart -> same XCD under %8 round-robin.
// Part p owns h-cols [64p,64p+64) of each LSTM layer and l-quarter
// [256p,256p+256) of attention. Monotone release/acquire flags sync the group.
// ---------------------------------------------------------------------------
__global__ __launch_bounds__(512) void speller(
    const unsigned short* __restrict__ keyT,
    const unsigned short* __restrict__ value,
    const unsigned short* __restrict__ Wl0,
    const unsigned short* __restrict__ Wl1,
    const unsigned short* __restrict__ Wl2,
    const unsigned short* __restrict__ qW0T,
    const unsigned short* __restrict__ qW1T,
    const float* __restrict__ bsum_p,
    const float* __restrict__ gep,
    const unsigned short* __restrict__ inithc,
    const unsigned short* __restrict__ initcc,
    const unsigned short* __restrict__ qb0c,
    const unsigned short* __restrict__ qb1c,
    const unsigned short* __restrict__ outWc,
    const unsigned short* __restrict__ outbc,
    const int* __restrict__ labels,
    const int* __restrict__ seq_lens,
    const int* __restrict__ dflags,
    int* __restrict__ syncflags,
    float* __restrict__ hbuf,
    float* __restrict__ pctxbuf,
    float* __restrict__ statbuf,
    void* __restrict__ out)
{
  __shared__ float inc[512];
  __shared__ float sacc[2048];
  __shared__ float garr[256];
  __shared__ float h0[256], h1[256], h2[256], ctx[256];
  __shared__ float cloc[3][64];
  __shared__ float xq[256];
  __shared__ float qv[64];
  __shared__ float sarr[256], earr[256];
  __shared__ float red[128];
  __shared__ float wf[4];
  const int tid = threadIdx.x;
  const int n = blockIdx.x & 63;
  const int p = blockIdx.x >> 6;
  const int f32o = dflags[0];
  const int i64 = dflags[1];
  const int slen = i64 ? seq_lens[2*n] : seq_lens[n];
  int* myflag = syncflags + (n*4 + p);

  if (tid < 256){ h0[tid]=b2f(inithc[tid]); h1[tid]=b2f(inithc[256+tid]); h2[tid]=b2f(inithc[512+tid]); }
  if (tid < 64){
    cloc[0][tid]=b2f(initcc[p*64+tid]);
    cloc[1][tid]=b2f(initcc[256+p*64+tid]);
    cloc[2][tid]=b2f(initcc[512+p*64+tid]);
  }
  __syncthreads();

  auto wait_peers = [&](int target){
    if (tid < 4 && tid != p){
      while (__hip_atomic_load(syncflags + (n*4+tid), __ATOMIC_ACQUIRE, __HIP_MEMORY_SCOPE_AGENT) < target) {}
    }
    __syncthreads();
  };
  auto publish = [&](int val){
    __syncthreads();   // all stores done & drained (vmcnt 0) before release
    if (tid == 0) __hip_atomic_store(myflag, val, __ATOMIC_RELEASE, __HIP_MEMORY_SCOPE_AGENT);
  };

  // LSTM gate slice from inc[512]; writes own h slice to hbuf, c kept local.
  auto lstm = [&](const unsigned short* W, const float* bs, const float* ger, int layer){
    const int gq = tid & 63, ks = tid >> 6;
    const unsigned short* wp = W + (size_t)p*131072 + (size_t)ks*16384 + gq*4;
    const float* xin = inc + ks*64;
    float a0=0.f,a1=0.f,a2=0.f,a3=0.f;
    #pragma unroll 8
    for (int k=0;k<64;k++){
      float x = xin[k];
      ushort4 w = *reinterpret_cast<const ushort4*>(wp + (size_t)k*256);
      a0 += x*b2f(w.x); a1 += x*b2f(w.y); a2 += x*b2f(w.z); a3 += x*b2f(w.w);
    }
    *reinterpret_cast<float4*>(&sacc[ks*256 + gq*4]) = make_float4(a0,a1,a2,a3);
    __syncthreads();
    if (tid < 256){
      float s = bs[tid] + (ger ? ger[tid] : 0.f);
      #pragma unroll
      for (int u=0;u<8;u++) s += sacc[u*256+tid];
      garr[tid] = s;
    }
    __syncthreads();
    if (tid < 64){
      float gi=garr[tid], gf=garr[64+tid], gg=garr[128+tid], go=garr[192+tid];
      float cc = sigf(gf)*cloc[layer][tid] + sigf(gi)*tanhf(gg);
      float hh = sigf(go)*tanhf(cc);
      cloc[layer][tid]=cc;
      hbuf[(n*3+layer)*256 + p*64 + tid] = hh;
    }
  };

  // attention: q-MLP (replicated), scores+softmax partials for own l-quarter,
  // partial ctx; one publish/wait; exact softmax assembly; fills ctx LDS.
  auto attn_stage = [&](int pubval){
    { // xq partials: col-pairs x 4 k-chunks of 64
      const int cp = tid & 127, kh = tid >> 7;
      float a0=0.f, a1=0.f;
      const unsigned short* qp = qW0T + 2*cp;
      #pragma unroll 4
      for (int k=0;k<64;k++){
        int kk = kh*64+k;
        ushort2 w = *reinterpret_cast<const ushort2*>(qp + (size_t)kk*256);
        float x = h2[kk];
        a0 += x*b2f(w.x); a1 += x*b2f(w.y);
      }
      sacc[kh*256 + 2*cp] = a0; sacc[kh*256 + 2*cp + 1] = a1;
    }
    __syncthreads();
    if (tid < 256){
      float s = sacc[tid]+sacc[256+tid]+sacc[512+tid]+sacc[768+tid];
      xq[tid] = eluf(s + b2f(qb0c[tid]));
    }
    __syncthreads();
    { // qv: 64 cols x 8 k-strips of 32
      const int qc = tid & 63, ks8 = tid >> 6;
      float a = 0.f;
      const unsigned short* qp = qW1T + qc;
      #pragma unroll 4
      for (int k=0;k<32;k++){ int kk = ks8*32+k; a += xq[kk]*b2f(qp[(size_t)kk*64]); }
      sacc[ks8*64+qc] = a;
    }
    __syncthreads();
    if (tid < 64){
      float s=0.f;
      #pragma unroll
      for (int u=0;u<8;u++) s += sacc[u*64+tid];
      qv[tid] = s + b2f(qb1c[tid]);
    }
    __syncthreads();
    { // scores own quarter: l-pairs x 4 q-chunks of 16
      const int lp = tid & 127, qh = tid >> 7;
      float a0=0.f,a1=0.f;
      const unsigned short* kp = keyT + (size_t)n*65536 + (size_t)qh*16*1024 + p*256 + 2*lp;
      #pragma unroll 4
      for (int q=0;q<16;q++){
        ushort2 w = *reinterpret_cast<const ushort2*>(kp + (size_t)q*1024);
        float qq = qv[qh*16+q];
        a0 += qq*b2f(w.x); a1 += qq*b2f(w.y);
      }
      sacc[qh*256+2*lp]=a0; sacc[qh*256+2*lp+1]=a1;
    }
    __syncthreads();
    if (tid < 256){
      float s = sacc[tid]+sacc[256+tid]+sacc[512+tid]+sacc[768+tid];
      sarr[tid] = (p*256+tid < slen) ? s : -1e30f;
    }
    __syncthreads();
    if (tid < 128) red[tid] = fmaxf(sarr[tid], sarr[tid+128]);
    __syncthreads();
    for (int s=64;s>0;s>>=1){ if (tid<s) red[tid]=fmaxf(red[tid],red[tid+s]); __syncthreads(); }
    const float pmax = red[0];
    __syncthreads();
    if (tid < 256) earr[tid] = (p*256+tid < slen) ? __expf(sarr[tid]-pmax) : 0.f;
    __syncthreads();
    if (tid < 128) red[tid] = earr[tid]+earr[tid+128];
    __syncthreads();
    for (int s=64;s>0;s>>=1){ if (tid<s) red[tid]+=red[tid+s]; __syncthreads(); }
    const float psum = red[0];
    { // partial ctx: h-pairs x 4 l-chunks of 64
      const int hp = tid & 127, lq = tid >> 7;
      float a0=0.f,a1=0.f;
      const unsigned short* vp = value + ((size_t)n*1024 + p*256 + lq*64)*256 + 2*hp;
      #pragma unroll 8
      for (int l=0;l<64;l++){
        ushort2 w = *reinterpret_cast<const ushort2*>(vp + (size_t)l*256);
        float e = earr[lq*64+l];
        a0 += e*b2f(w.x); a1 += e*b2f(w.y);
      }
      sacc[lq*256+2*hp]=a0; sacc[lq*256+2*hp+1]=a1;
    }
    __syncthreads();
    if (tid < 256)
      pctxbuf[((size_t)n*4+p)*256 + tid] = sacc[tid]+sacc[256+tid]+sacc[512+tid]+sacc[768+tid];
    if (tid == 0){ statbuf[(n*4+p)*2] = pmax; statbuf[(n*4+p)*2+1] = psum; }
    publish(pubval);
    wait_peers(pubval);
    if (tid == 0){
      float m0=statbuf[n*8+0], s0=statbuf[n*8+1], m1=statbuf[n*8+2], s1=statbuf[n*8+3];
      float m2=statbuf[n*8+4], s2=statbuf[n*8+5], m3=statbuf[n*8+6], s3=statbuf[n*8+7];
      float M = fmaxf(fmaxf(m0,m1),fmaxf(m2,m3));
      float w0=__expf(m0-M), w1=__expf(m1-M), w2=__expf(m2-M), w3=__expf(m3-M);
      float inv = 1.f/(s0*w0+s1*w1+s2*w2+s3*w3);
      wf[0]=w0*inv; wf[1]=w1*inv; wf[2]=w2*inv; wf[3]=w3*inv;
    }
    __syncthreads();
    if (tid < 256){
      const float* pb = pctxbuf + (size_t)n*1024 + tid;
      ctx[tid] = pb[0]*wf[0] + pb[256]*wf[1] + pb[512]*wf[2] + pb[768]*wf[3];
    }
    __syncthreads();
  };

  attn_stage(1);   // initial prev_ctx from inith[2]

  for (int t=0;t<256;t++){
    const int lab = i64 ? labels[2*(t*64+n)] : labels[t*64+n];
    // stage A: L0 uses {ctx, h0_prev}
    if (tid < 256){ inc[tid]=ctx[tid]; inc[256+tid]=h0[tid]; }
    __syncthreads();
    lstm(Wl0, bsum_p + p*256, gep + ((size_t)p*34+lab)*256, 0);
    publish(4*t+2);
    // stage B: L1 uses {h0_new, h1_prev}
    wait_peers(4*t+2);
    if (tid < 256){ float v = hbuf[(n*3+0)*256+tid]; h0[tid]=v; inc[tid]=v; inc[256+tid]=h1[tid]; }
    __syncthreads();
    lstm(Wl1, bsum_p + 1024 + p*256, nullptr, 1);
    publish(4*t+3);
    // stage C: L2 uses {h1_new, h2_prev}
    wait_peers(4*t+3);
    if (tid < 256){ float v = hbuf[(n*3+1)*256+tid]; h1[tid]=v; inc[tid]=v; inc[256+tid]=h2[tid]; }
    __syncthreads();
    lstm(Wl2, bsum_p + 2048 + p*256, nullptr, 2);
    publish(4*t+4);
    // stage D: attention with fresh h2
    wait_peers(4*t+4);
    if (tid < 256) h2[tid] = hbuf[(n*3+2)*256+tid];
    __syncthreads();
    attn_stage(4*t+5);
    // out projection: row r = 4*ri + p (+ rows 32,33 on parts 0,1)
    {
      const int ri = tid >> 6, kk = tid & 63;
      const int r = 4*ri + p;
      float acc = 0.f;
      const unsigned short* wr = outWc + (size_t)r*512 + kk;
      #pragma unroll
      for (int s=0;s<4;s++) acc += ctx[s*64+kk]*b2f(wr[s*64]);
      #pragma unroll
      for (int s=0;s<4;s++) acc += h2[s*64+kk]*b2f(wr[256+s*64]);
      #pragma unroll
      for (int off=32; off>0; off>>=1) acc += __shfl_down(acc, off);
      if (kk==0){
        float v = acc + b2f(outbc[r]);
        size_t oi = ((size_t)(t*64+n))*34 + r;
        if (f32o) ((float*)out)[oi]=v; else ((unsigned short*)out)[oi]=f2b(v);
      }
      if (p < 2 && tid < 64){
        const int r2 = 32+p;
        float a2=0.f;
        const unsigned short* wr2 = outWc + (size_t)r2*512 + tid;
        #pragma unroll
        for (int s=0;s<4;s++) a2 += ctx[s*64+tid]*b2f(wr2[s*64]);
        #pragma unroll
        for (int s=0;s<4;s++) a2 += h2[s*64+tid]*b2f(wr2[256+s*64]);
        #pragma unroll
        for (int off=32; off>0; off>>=1) a2 += __shfl_down(a2, off);
        if (tid==0){
          float v = a2 + b2f(outbc[r2]);
          size_t oi = ((size_t)(t*64+n))*34 + r2;
          if (f32o) ((float*)out)[oi]=v; else ((unsigned short*)out)[oi]=f2b(v);
        }
      }
    }
  }
}

extern "C" void kernel_launch(void* const* d_in, const int* in_sizes, int n_in,
                              void* d_out, int out_size, void* d_ws, size_t ws_size,
                              hipStream_t stream) {
  const void* seqs  = d_in[0];
  const int* seq_lens = (const int*)d_in[1];
  const int* labels   = (const int*)d_in[2];
  const void* emb   = d_in[3];
  const void* inith = d_in[4];
  const void* initc = d_in[5];
  const void* Wih0 = d_in[6];  const void* Whh0 = d_in[7];
  const void* bih0 = d_in[8];  const void* bhh0 = d_in[9];
  const void* Wih1 = d_in[10]; const void* Whh1 = d_in[11];
  const void* bih1 = d_in[12]; const void* bhh1 = d_in[13];
  const void* Wih2 = d_in[14]; const void* Whh2 = d_in[15];
  const void* bih2 = d_in[16]; const void* bhh2 = d_in[17];
  const void* qW0 = d_in[18];  const void* qb0 = d_in[19];
  const void* qW1 = d_in[20];  const void* qb1 = d_in[21];
  const void* kW0 = d_in[22];  const void* kb0 = d_in[23];
  const void* kW1 = d_in[24];  const void* kb1 = d_in[25];
  const void* vW0 = d_in[26];  const void* vb0 = d_in[27];
  const void* vW1 = d_in[28];  const void* vb1 = d_in[29];
  const void* outW = d_in[30]; const void* outb = d_in[31];

  char* ws = (char*)d_ws;
  unsigned short* keyT  = (unsigned short*)(ws);             //  8,388,608 B  [64][64][1024]
  unsigned short* value = (unsigned short*)(ws + 8388608);   // 33,554,432 B  [64][1024][256]
  unsigned short* Wl0   = (unsigned short*)(ws + 41943040);  //  1,048,576 B  [4][512][256]
  unsigned short* Wl1   = (unsigned short*)(ws + 42991616);
  unsigned short* Wl2   = (unsigned short*)(ws + 44040192);
  unsigned short* kW0T  = (unsigned short*)(ws + 45088768);  //    524,288 B (prep-phase only)
  unsigned short* kW1T  = (unsigned short*)(ws + 45613056);  //     65,536 B (prep-phase only)
  unsigned short* vW0T  = (unsigned short*)(ws + 45678592);  //    262,144 B
  unsigned short* vW1T  = (unsigned short*)(ws + 45940736);  //    131,072 B
  unsigned short* qW0T  = (unsigned short*)(ws + 46071808);  //    131,072 B
  unsigned short* qW1T  = (unsigned short*)(ws + 46202880);  //     32,768 B
  float*          bsum  = (float*)(ws + 46235648);           //     12,288 B  [3][4][256]
  float*          gep   = (float*)(ws + 46247936);           //    139,264 B  [4][34][256]
  unsigned short* outWc = (unsigned short*)(ws + 46387200);  //     34,816 B
  unsigned short* inithc= (unsigned short*)(ws + 46422016);  //      1,536 B
  unsigned short* initcc= (unsigned short*)(ws + 46423552);  //      1,536 B
  unsigned short* qb0c  = (unsigned short*)(ws + 46425088);  //        512 B
  unsigned short* qb1c  = (unsigned short*)(ws + 46425600);  //        128 B
  unsigned short* outbc = (unsigned short*)(ws + 46425728);  //        128 B
  int*            dflags= (int*)(ws + 46425856);             //         16 B
  // sync region overlaps kW0T/kW1T (consumed before speller starts):
  int*   syncflags = (int*)(ws + 45088768);                  //      1,024 B  [64][4]
  float* hbuf      = (float*)(ws + 45089792);                //    196,608 B  [64][3][256]
  float* pctxbuf   = (float*)(ws + 45286400);                //    262,144 B  [64][4][256]
  float* statbuf   = (float*)(ws + 45548544);                //      2,048 B  [64][4][2]

  sniff<<<dim3(1), dim3(64), 0, stream>>>(seqs, seq_lens, dflags);
  prep_transpose<<<dim3(8472), dim3(256), 0, stream>>>(
      Wih0,Whh0,Wih1,Whh1,Wih2,Whh2, kW0,kW1,vW0,vW1,qW0,qW1,
      bih0,bhh0,bih1,bhh1,bih2,bhh2,
      outW,inith,initc,qb0,qb1,outb, dflags,
      Wl0,Wl1,Wl2,kW0T,kW1T,vW0T,vW1T,qW0T,qW1T,bsum,
      outWc,inithc,initcc,qb0c,qb1c,outbc);
  prep_ge<<<dim3(34), dim3(256), 0, stream>>>(emb, Wih0, dflags, gep);
  key_mlp<<<dim3(4096), dim3(256), 0, stream>>>(seqs, kW0T, kb0, kW1T, kb1, dflags, keyT);
  value_mlp<<<dim3(4096), dim3(256), 0, stream>>>(seqs, vW0T, vb0, vW1T, vb1, dflags, value);
  zero_sync<<<dim3(1), dim3(256), 0, stream>>>(syncflags);
  speller<<<dim3(256), dim3(512), 0, stream>>>(
      keyT, value, Wl0, Wl1, Wl2, qW0T, qW1T, bsum, gep,
      inithc, initcc, qb0c, qb1c, outWc, outbc, labels, seq_lens, dflags,
      syncflags, hbuf, pctxbuf, statbuf, d_out);
}

// Round 5
// 11288.912 us; speedup vs baseline: 5.0892x; 2.0717x over previous
//
#include <hip/hip_runtime.h>
#include <cstddef>

#define DEV static __device__ __forceinline__

DEV float b2f(unsigned short u){ unsigned int i=((unsigned int)u)<<16; float f; __builtin_memcpy(&f,&i,4); return f; }
DEV float lo16(unsigned int u){ unsigned int i=u<<16; float f; __builtin_memcpy(&f,&i,4); return f; }
DEV float hi16(unsigned int u){ unsigned int i=u&0xffff0000u; float f; __builtin_memcpy(&f,&i,4); return f; }
DEV unsigned short f2b(float f){ unsigned int i; __builtin_memcpy(&i,&f,4); unsigned int r=(i+0x7fffu+((i>>16)&1u))>>16; return (unsigned short)r; }
DEV float sigf(float x){ return 1.f/(1.f+__expf(-x)); }
DEV float eluf(float x){ return x>0.f ? x : (__expf(x)-1.f); }
DEV float gload(const void* p, long i, int f32){
  return f32 ? ((const float*)p)[i] : b2f(((const unsigned short*)p)[i]);
}
// relaxed agent-scope atomics: LLC-coherent, NO L1/L2 invalidation (unlike acq/rel)
DEV void ast(float* p, float v){ __hip_atomic_store(p, v, __ATOMIC_RELAXED, __HIP_MEMORY_SCOPE_AGENT); }
DEV float ald(const float* p){ return __hip_atomic_load(p, __ATOMIC_RELAXED, __HIP_MEMORY_SCOPE_AGENT); }

// ---------------------------------------------------------------------------
// Sniff input dtypes from raw bits. flags[0]=1 if floats are f32, flags[1]=1
// if ints are i64.
// ---------------------------------------------------------------------------
__global__ __launch_bounds__(64) void sniff(const void* __restrict__ seqs,
                                            const void* __restrict__ seq_lens,
                                            int* __restrict__ flags)
{
  __shared__ int cnt;
  if (threadIdx.x==0) cnt=0;
  __syncthreads();
  const unsigned short* u = (const unsigned short*)seqs;
  int sane=0;
  for (int i=threadIdx.x;i<1024;i+=64){
    int e = (u[i]>>7)&0xFF;
    if (e>=0x70 && e<=0x8F) sane++;
  }
  atomicAdd(&cnt, sane);
  __syncthreads();
  if (threadIdx.x==0){
    flags[0] = (cnt < 820) ? 1 : 0;
    const int* s = (const int*)seq_lens;
    flags[1] = ((s[1]|s[3]|s[5]|s[7])==0) ? 1 : 0;
  }
}

// ---------------------------------------------------------------------------
// Prep: part-sliced bf16 weights.
// Wl[l][part][k][gi]: gi in [0,256): type=gi>>6, jj=gi&63,
// g = type*256 + part*64 + jj.  k<256 -> ih (ctx/h_in), k>=256 -> hh.
// ---------------------------------------------------------------------------
__global__ __launch_bounds__(256) void prep_transpose(
    const void* __restrict__ Wih0, const void* __restrict__ Whh0,
    const void* __restrict__ Wih1, const void* __restrict__ Whh1,
    const void* __restrict__ Wih2, const void* __restrict__ Whh2,
    const void* __restrict__ kW0,  const void* __restrict__ kW1,
    const void* __restrict__ vW0,  const void* __restrict__ vW1,
    const void* __restrict__ qW0,  const void* __restrict__ qW1,
    const void* __restrict__ bih0, const void* __restrict__ bhh0,
    const void* __restrict__ bih1, const void* __restrict__ bhh1,
    const void* __restrict__ bih2, const void* __restrict__ bhh2,
    const void* __restrict__ outW, const void* __restrict__ inith,
    const void* __restrict__ initc, const void* __restrict__ qb0,
    const void* __restrict__ qb1,  const void* __restrict__ outb,
    const int* __restrict__ flags,
    unsigned short* __restrict__ Wl0, unsigned short* __restrict__ Wl1,
    unsigned short* __restrict__ Wl2,
    unsigned short* __restrict__ kW0T, unsigned short* __restrict__ kW1T,
    unsigned short* __restrict__ vW0T, unsigned short* __restrict__ vW1T,
    unsigned short* __restrict__ qW0T, unsigned short* __restrict__ qW1T,
    float* __restrict__ bsum,
    unsigned short* __restrict__ outWc, unsigned short* __restrict__ inithc,
    unsigned short* __restrict__ initcc, unsigned short* __restrict__ qb0c,
    unsigned short* __restrict__ qb1c,  unsigned short* __restrict__ outbc)
{
  const int f32 = flags[0];
  int idx = blockIdx.x*256 + threadIdx.x;
  if (idx < 524288){ int r=idx&131071, k=r>>8, gi=r&255;
    int g = ((gi>>6)<<8) + ((idx>>17)<<6) + (gi&63);
    Wl0[idx] = f2b((k<256)? gload(Wih0,(long)g*512+k,f32) : gload(Whh0,(long)g*256+(k-256),f32)); return; }
  idx -= 524288;
  if (idx < 524288){ int r=idx&131071, k=r>>8, gi=r&255;
    int g = ((gi>>6)<<8) + ((idx>>17)<<6) + (gi&63);
    Wl1[idx] = f2b((k<256)? gload(Wih1,(long)g*256+k,f32) : gload(Whh1,(long)g*256+(k-256),f32)); return; }
  idx -= 524288;
  if (idx < 524288){ int r=idx&131071, k=r>>8, gi=r&255;
    int g = ((gi>>6)<<8) + ((idx>>17)<<6) + (gi&63);
    Wl2[idx] = f2b((k<256)? gload(Wih2,(long)g*256+k,f32) : gload(Whh2,(long)g*256+(k-256),f32)); return; }
  idx -= 524288;
  if (idx < 262144){ int k=idx>>9, j=idx&511; kW0T[idx]=f2b(gload(kW0,(long)j*512+k,f32)); return; }
  idx -= 262144;
  if (idx < 32768){ int k=idx>>6, j=idx&63; kW1T[idx]=f2b(gload(kW1,(long)j*512+k,f32)); return; }
  idx -= 32768;
  if (idx < 131072){ int k=idx>>8, j=idx&255; vW0T[idx]=f2b(gload(vW0,(long)j*512+k,f32)); return; }
  idx -= 131072;
  if (idx < 65536){ int k=idx>>8, j=idx&255; vW1T[idx]=f2b(gload(vW1,(long)j*256+k,f32)); return; }
  idx -= 65536;
  if (idx < 65536){ int k=idx>>8, j=idx&255; qW0T[idx]=f2b(gload(qW0,(long)j*256+k,f32)); return; }
  idx -= 65536;
  if (idx < 16384){ int k=idx>>6, j=idx&63; qW1T[idx]=f2b(gload(qW1,(long)j*256+k,f32)); return; }
  idx -= 16384;
  if (idx < 3072){ int l=idx>>10, r=idx&1023, pp=r>>8, gi=r&255;
    int g = ((gi>>6)<<8) + (pp<<6) + (gi&63);
    const void* bi = (l==0)?bih0:((l==1)?bih1:bih2);
    const void* bh = (l==0)?bhh0:((l==1)?bhh1:bhh2);
    bsum[idx] = gload(bi,g,f32)+gload(bh,g,f32); return; }
  idx -= 3072;
  if (idx < 17408){ outWc[idx]=f2b(gload(outW,idx,f32)); return; }
  idx -= 17408;
  if (idx < 768){ inithc[idx]=f2b(gload(inith,idx,f32)); return; }
  idx -= 768;
  if (idx < 768){ initcc[idx]=f2b(gload(initc,idx,f32)); return; }
  idx -= 768;
  if (idx < 256){ qb0c[idx]=f2b(gload(qb0,idx,f32)); return; }
  idx -= 256;
  if (idx < 64){ qb1c[idx]=f2b(gload(qb1,idx,f32)); return; }
  idx -= 64;
  if (idx < 34){ outbc[idx]=f2b(gload(outb,idx,f32)); return; }
}

// gep[part][v][gi] = sum_k emb[v][k] * Wih0[g(part,gi)][256+k]
__global__ __launch_bounds__(256) void prep_ge(
    const void* __restrict__ emb,
    const void* __restrict__ Wih0,
    const int* __restrict__ flags,
    float* __restrict__ gep)
{
  __shared__ float ev[256];
  const int f32 = flags[0];
  const int v = blockIdx.x, tid = threadIdx.x;
  ev[tid] = gload(emb,(long)v*256+tid,f32);
  __syncthreads();
  #pragma unroll
  for (int j=0;j<4;j++){
    const int g = tid*4+j;
    float a = 0.f;
    #pragma unroll 4
    for (int k=0;k<256;k++) a += ev[k]*gload(Wih0,(long)g*512+256+k,f32);
    int pp = (g>>6)&3, gi = ((g>>8)<<6)|(g&63);
    gep[((size_t)pp*34+v)*256+gi] = a;
  }
}

// ---------------------------------------------------------------------------
// key MLP: keyT[n][q][l]
// ---------------------------------------------------------------------------
__global__ __launch_bounds__(256) void key_mlp(
    const void* __restrict__ seqs,
    const unsigned short* __restrict__ kW0T, const void* __restrict__ kb0,
    const unsigned short* __restrict__ kW1T, const void* __restrict__ kb1,
    const int* __restrict__ flags,
    unsigned short* __restrict__ keyT)
{
  __shared__ float Xt[16*512];
  __shared__ unsigned short Hd[16*512];
  const int f32 = flags[0];
  const int tid = threadIdx.x;
  const int R0 = blockIdx.x*16;
  for (int i=tid;i<8192;i+=256) Xt[i] = gload(seqs,(long)R0*512+i,f32);
  __syncthreads();
  {
    const int j0 = 2*tid;
    float acc0[16], acc1[16];
    #pragma unroll
    for (int r=0;r<16;r++){ acc0[r]=0.f; acc1[r]=0.f; }
    for (int k=0;k<512;k++){
      ushort2 w = *reinterpret_cast<const ushort2*>(kW0T + (size_t)k*512 + j0);
      float w0=b2f(w.x), w1=b2f(w.y);
      #pragma unroll
      for (int r=0;r<16;r++){ float x = Xt[r*512+k]; acc0[r]+=x*w0; acc1[r]+=x*w1; }
    }
    float b0v=gload(kb0,j0,f32), b1v=gload(kb0,j0+1,f32);
    #pragma unroll
    for (int r=0;r<16;r++){
      Hd[r*512+j0]   = f2b(eluf(acc0[r]+b0v));
      Hd[r*512+j0+1] = f2b(eluf(acc1[r]+b1v));
    }
  }
  __syncthreads();
  {
    const int j = tid & 63;
    const int rbase = tid >> 6;
    float acc[4] = {0.f,0.f,0.f,0.f};
    for (int k=0;k<512;k++){
      float w = b2f(kW1T[(size_t)k*64 + j]);
      #pragma unroll
      for (int m=0;m<4;m++) acc[m] += b2f(Hd[(rbase+4*m)*512 + k]) * w;
    }
    float bv = gload(kb1,j,f32);
    #pragma unroll
    for (int m=0;m<4;m++){
      int R = R0 + rbase + 4*m;
      int l = R >> 6, n = R & 63;
      keyT[((size_t)(n*64 + j))*1024 + l] = f2b(acc[m]+bv);
    }
  }
}

// ---------------------------------------------------------------------------
// value MLP: value[n][l][h]
// ---------------------------------------------------------------------------
__global__ __launch_bounds__(256) void value_mlp(
    const void* __restrict__ seqs,
    const unsigned short* __restrict__ vW0T, const void* __restrict__ vb0,
    const unsigned short* __restrict__ vW1T, const void* __restrict__ vb1,
    const int* __restrict__ flags,
    unsigned short* __restrict__ value)
{
  __shared__ float Xt[16*512];
  __shared__ float Hd[16*256];
  const int f32 = flags[0];
  const int tid = threadIdx.x;
  const int R0 = blockIdx.x*16;
  for (int i=tid;i<8192;i+=256) Xt[i] = gload(seqs,(long)R0*512+i,f32);
  __syncthreads();
  {
    const int j0 = 2*(tid & 127);
    const int rh = tid >> 7;
    float acc0[8], acc1[8];
    #pragma unroll
    for (int r=0;r<8;r++){ acc0[r]=0.f; acc1[r]=0.f; }
    for (int k=0;k<512;k++){
      ushort2 w = *reinterpret_cast<const ushort2*>(vW0T + (size_t)k*256 + j0);
      float w0=b2f(w.x), w1=b2f(w.y);
      #pragma unroll
      for (int r=0;r<8;r++){ float x = Xt[(rh*8+r)*512+k]; acc0[r]+=x*w0; acc1[r]+=x*w1; }
    }
    float b0v=gload(vb0,j0,f32), b1v=gload(vb0,j0+1,f32);
    #pragma unroll
    for (int r=0;r<8;r++){
      Hd[(rh*8+r)*256+j0]   = eluf(acc0[r]+b0v);
      Hd[(rh*8+r)*256+j0+1] = eluf(acc1[r]+b1v);
    }
  }
  __syncthreads();
  {
    const int j = tid;
    float acc[16];
    #pragma unroll
    for (int r=0;r<16;r++) acc[r]=0.f;
    for (int k=0;k<256;k++){
      float w = b2f(vW1T[(size_t)k*256 + j]);
      #pragma unroll
      for (int r=0;r<16;r++) acc[r] += Hd[r*256+k]*w;
    }
    float bv = gload(vb1,j,f32);
    #pragma unroll
    for (int r=0;r<16;r++){
      int R = R0 + r; int l = R>>6, n = R&63;
      value[((size_t)n*1024 + l)*256 + j] = f2b(acc[r]+bv);
    }
  }
}

__global__ __launch_bounds__(256) void zero_sync(int* __restrict__ f){
  f[threadIdx.x] = 0;
}

// ---------------------------------------------------------------------------
// Decode: 256 blocks x 512 threads, 1 block/CU (LDS-bound). Block (p,n).
// Part p owns h-cols [64p,64p+64) of each layer and l-quarter of attention;
// its value quarter (128 KB) lives in dynamic LDS for the whole kernel.
// Cross-part exchange via RELAXED agent atomics (LLC) — no cache invalidation.
// ---------------------------------------------------------------------------
__global__ __launch_bounds__(512, 1) void speller(
    const unsigned short* __restrict__ keyT,
    const unsigned short* __restrict__ value,
    const unsigned short* __restrict__ Wl0,
    const unsigned short* __restrict__ Wl1,
    const unsigned short* __restrict__ Wl2,
    const unsigned short* __restrict__ qW0T,
    const unsigned short* __restrict__ qW1T,
    const float* __restrict__ bsum_p,
    const float* __restrict__ gep,
    const unsigned short* __restrict__ inithc,
    const unsigned short* __restrict__ initcc,
    const unsigned short* __restrict__ qb0c,
    const unsigned short* __restrict__ qb1c,
    const unsigned short* __restrict__ outWc,
    const unsigned short* __restrict__ outbc,
    const int* __restrict__ labels,
    const int* __restrict__ seq_lens,
    const int* __restrict__ dflags,
    int* __restrict__ syncflags,
    float* __restrict__ hbuf,
    void* __restrict__ out)
{
  extern __shared__ char smem_dyn[];
  unsigned short* vlds = (unsigned short*)smem_dyn;   // [256 l][256 h] quarter, 128 KB

  __shared__ float sacc[4096];
  __shared__ float inc[512];
  __shared__ float garr[256];
  __shared__ float h0[256], h1[256], h2[256], ctx[256];
  __shared__ float cloc[3][64];
  __shared__ float h2s[64];
  __shared__ float xq[256];
  __shared__ float qv[64];
  __shared__ float sarr[256], earr[256];
  __shared__ float red[128];
  __shared__ float wf[4];

  const int tid = threadIdx.x;
  const int n = blockIdx.x & 63;
  const int p = blockIdx.x >> 6;
  const int f32o = dflags[0];
  const int i64 = dflags[1];
  const int slen = i64 ? seq_lens[2*n] : seq_lens[n];

  float* hb   = hbuf + (size_t)n*3072;
  float* H0b  = hb;          // [256]
  float* H1b  = hb + 256;    // [256]
  float* H2b  = hb + 512;    // [256]
  float* XQP  = hb + 768;    // [4][256]
  float* PCTX = hb + 1792;   // [4][256]
  float* STAT = hb + 2816;   // [4][2]
  int* myflag = syncflags + (n*4 + p);

  // preload value quarter into LDS (once)
  {
    const uint4* src = (const uint4*)(value + ((size_t)n*1024 + p*256)*256);
    uint4* dst = (uint4*)vlds;
    for (int i=tid;i<16384;i+=512) dst[i] = src[i];
  }
  if (tid < 256){ h0[tid]=b2f(inithc[tid]); h1[tid]=b2f(inithc[256+tid]); h2[tid]=b2f(inithc[512+tid]); }
  if (tid < 64){
    cloc[0][tid]=b2f(initcc[p*64+tid]);
    cloc[1][tid]=b2f(initcc[256+p*64+tid]);
    cloc[2][tid]=b2f(initcc[512+p*64+tid]);
    float hh = b2f(inithc[512+p*64+tid]);
    h2s[tid] = hh;
    ast(H2b + p*64 + tid, hh);
  }
  __syncthreads();

  auto publish = [&](int val){
    __syncthreads();   // drains vmcnt(0) before s_barrier -> payload at LLC
    if (tid == 0) __hip_atomic_store(myflag, val, __ATOMIC_RELAXED, __HIP_MEMORY_SCOPE_AGENT);
  };
  auto wait_peers = [&](int target){
    if (tid < 4 && tid != p){
      while (__hip_atomic_load(syncflags + (n*4+tid), __ATOMIC_RELAXED, __HIP_MEMORY_SCOPE_AGENT) < target) {}
    }
    __syncthreads();
  };

  // LSTM gate slice from inc[512]; h slice -> hbuf (atomic), c local.
  auto lstm = [&](const unsigned short* W, const float* bs, const float* ger,
                  int layer, float* Hdst){
    const int go8 = tid & 31;   // gate oct: gi = go8*8..+8
    const int ks  = tid >> 5;   // k-chunk 0..15 (32 k each)
    const unsigned short* wp = W + (size_t)p*131072 + (size_t)ks*32*256 + go8*8;
    const float* xin = inc + ks*32;
    float a0=0.f,a1=0.f,a2=0.f,a3=0.f,a4=0.f,a5=0.f,a6=0.f,a7=0.f;
    #pragma unroll 16
    for (int k=0;k<32;k++){
      float x = xin[k];
      uint4 w = *reinterpret_cast<const uint4*>(wp + (size_t)k*256);
      a0 += x*lo16(w.x); a1 += x*hi16(w.x);
      a2 += x*lo16(w.y); a3 += x*hi16(w.y);
      a4 += x*lo16(w.z); a5 += x*hi16(w.z);
      a6 += x*lo16(w.w); a7 += x*hi16(w.w);
    }
    float* sb = sacc + ks*256 + go8*8;
    sb[0]=a0; sb[1]=a1; sb[2]=a2; sb[3]=a3; sb[4]=a4; sb[5]=a5; sb[6]=a6; sb[7]=a7;
    __syncthreads();
    if (tid < 256){
      float s = bs[tid] + (ger ? ger[tid] : 0.f);
      #pragma unroll
      for (int u=0;u<16;u++) s += sacc[u*256+tid];
      garr[tid] = s;
    }
    __syncthreads();
    if (tid < 64){
      float gi=garr[tid], gf=garr[64+tid], gg=garr[128+tid], go=garr[192+tid];
      float cc = sigf(gf)*cloc[layer][tid] + sigf(gi)*tanhf(gg);
      float hh = sigf(go)*tanhf(cc);
      cloc[layer][tid]=cc;
      if (layer==2) h2s[tid]=hh;
      ast(Hdst + p*64 + tid, hh);
    }
  };

  // attention in two LLC rounds: (v1) xq-partials + fresh h2 slice already
  // stored; (v2) softmax stats + partial ctx. Exact softmax assembly.
  auto attn_stage = [&](int v1, int v2){
    // BARRIER: stage C's lstm writes h2s[] from wave 0 only (tid<64) with no
    // trailing sync; all 512 threads read h2s below. (Round-4 bug: missing
    // this barrier caused one-step-stale h2s -> absmax 3e-2.)
    __syncthreads();
    { // xq partials from OWN h2 slice (split-k): rows [64p,64p+64) of qW0T
      const int j = tid & 255, kh = tid >> 8;
      const unsigned short* qp = qW0T + ((size_t)(p*64 + kh*32))*256 + j;
      float a = 0.f;
      #pragma unroll 8
      for (int k=0;k<32;k++) a += h2s[kh*32+k]*b2f(qp[(size_t)k*256]);
      sacc[kh*256 + j] = a;
    }
    __syncthreads();
    if (tid < 256) ast(XQP + p*256 + tid, sacc[tid]+sacc[256+tid]);
    publish(v1);
    wait_peers(v1);
    if (tid < 256){
      float s = ald(XQP+tid) + ald(XQP+256+tid) + ald(XQP+512+tid) + ald(XQP+768+tid);
      xq[tid] = eluf(s + b2f(qb0c[tid]));
      h2[tid] = ald(H2b + tid);
    }
    __syncthreads();
    { // qv (replicated): 64 cols x 8 k-strips of 32
      const int qc = tid & 63, k8 = tid >> 6;
      float a = 0.f;
      const unsigned short* qp = qW1T + qc;
      #pragma unroll 8
      for (int k=0;k<32;k++){ int kk = k8*32+k; a += xq[kk]*b2f(qp[(size_t)kk*64]); }
      sacc[k8*64+qc] = a;
    }
    __syncthreads();
    if (tid < 64){
      float s=0.f;
      #pragma unroll
      for (int u=0;u<8;u++) s += sacc[u*64+tid];
      qv[tid] = s + b2f(qb1c[tid]);
    }
    __syncthreads();
    { // scores own l-quarter (keyT global, 32 KB): l-pairs x 4 q-chunks of 16
      const int lp = tid & 127, qh = tid >> 7;
      float a0=0.f,a1=0.f;
      const unsigned short* kp = keyT + (size_t)n*65536 + (size_t)qh*16*1024 + p*256 + 2*lp;
      #pragma unroll 8
      for (int q=0;q<16;q++){
        ushort2 w = *reinterpret_cast<const ushort2*>(kp + (size_t)q*1024);
        float qq = qv[qh*16+q];
        a0 += qq*b2f(w.x); a1 += qq*b2f(w.y);
      }
      sacc[qh*256+2*lp]=a0; sacc[qh*256+2*lp+1]=a1;
    }
    __syncthreads();
    if (tid < 256){
      float s = sacc[tid]+sacc[256+tid]+sacc[512+tid]+sacc[768+tid];
      sarr[tid] = (p*256+tid < slen) ? s : -1e30f;
    }
    __syncthreads();
    if (tid < 128) red[tid] = fmaxf(sarr[tid], sarr[tid+128]);
    __syncthreads();
    for (int s=64;s>0;s>>=1){ if (tid<s) red[tid]=fmaxf(red[tid],red[tid+s]); __syncthreads(); }
    const float pmax = red[0];
    __syncthreads();
    if (tid < 256) earr[tid] = (p*256+tid < slen) ? __expf(sarr[tid]-pmax) : 0.f;
    __syncthreads();
    if (tid < 128) red[tid] = earr[tid]+earr[tid+128];
    __syncthreads();
    for (int s=64;s>0;s>>=1){ if (tid<s) red[tid]+=red[tid+s]; __syncthreads(); }
    const float psum = red[0];
    { // partial ctx from LDS value: h-pairs x 4 l-chunks of 64
      const int hp = tid & 127, lq = tid >> 7;
      float a0=0.f,a1=0.f;
      const unsigned short* vp = vlds + (size_t)(lq*64)*256 + 2*hp;
      #pragma unroll 8
      for (int l=0;l<64;l++){
        ushort2 w = *reinterpret_cast<const ushort2*>(vp + (size_t)l*256);
        float e = earr[lq*64+l];
        a0 += e*b2f(w.x); a1 += e*b2f(w.y);
      }
      sacc[lq*256+2*hp]=a0; sacc[lq*256+2*hp+1]=a1;
    }
    __syncthreads();
    if (tid < 256) ast(PCTX + p*256 + tid, sacc[tid]+sacc[256+tid]+sacc[512+tid]+sacc[768+tid]);
    if (tid == 0){ ast(STAT + p*2, pmax); ast(STAT + p*2 + 1, psum); }
    publish(v2);
    wait_peers(v2);
    if (tid == 0){
      float m0=ald(STAT+0), s0=ald(STAT+1), m1=ald(STAT+2), s1=ald(STAT+3);
      float m2=ald(STAT+4), s2=ald(STAT+5), m3=ald(STAT+6), s3=ald(STAT+7);
      float M = fmaxf(fmaxf(m0,m1),fmaxf(m2,m3));
      float w0=__expf(m0-M), w1=__expf(m1-M), w2=__expf(m2-M), w3=__expf(m3-M);
      float inv = 1.f/(s0*w0+s1*w1+s2*w2+s3*w3);
      wf[0]=w0*inv; wf[1]=w1*inv; wf[2]=w2*inv; wf[3]=w3*inv;
    }
    __syncthreads();
    if (tid < 256){
      ctx[tid] = ald(PCTX+tid)*wf[0] + ald(PCTX+256+tid)*wf[1]
               + ald(PCTX+512+tid)*wf[2] + ald(PCTX+768+tid)*wf[3];
    }
    __syncthreads();
  };

  attn_stage(1, 2);   // initial prev_ctx from inith[2]

  for (int t=0;t<256;t++){
    const int lab = i64 ? labels[2*(t*64+n)] : labels[t*64+n];
    // stage A: L0 uses {ctx, h0_prev}
    if (tid < 256){ inc[tid]=ctx[tid]; inc[256+tid]=h0[tid]; }
    __syncthreads();
    lstm(Wl0, bsum_p + p*256, gep + ((size_t)p*34+lab)*256, 0, H0b);
    publish(4*t+3);
    wait_peers(4*t+3);
    // stage B: L1 uses {h0_new, h1_prev}
    if (tid < 256){ float v = ald(H0b+tid); h0[tid]=v; inc[tid]=v; inc[256+tid]=h1[tid]; }
    __syncthreads();
    lstm(Wl1, bsum_p + 1024 + p*256, nullptr, 1, H1b);
    publish(4*t+4);
    wait_peers(4*t+4);
    // stage C: L2 uses {h1_new, h2_prev}
    if (tid < 256){ float v = ald(H1b+tid); h1[tid]=v; inc[tid]=v; inc[256+tid]=h2[tid]; }
    __syncthreads();
    lstm(Wl2, bsum_p + 2048 + p*256, nullptr, 2, H2b);
    // stage D: attention (round 1 payload = h2 slice + xq partials);
    // attn_stage opens with the barrier that orders h2s.
    attn_stage(4*t+5, 4*t+6);
    // out projection: rows r = 4*ri + p (+ rows 32,33 on parts 0,1)
    {
      const int ri = tid >> 6, kk = tid & 63;
      const int r = 4*ri + p;
      float acc = 0.f;
      const unsigned short* wr = outWc + (size_t)r*512 + kk;
      #pragma unroll
      for (int s=0;s<4;s++) acc += ctx[s*64+kk]*b2f(wr[s*64]);
      #pragma unroll
      for (int s=0;s<4;s++) acc += h2[s*64+kk]*b2f(wr[256+s*64]);
      #pragma unroll
      for (int off=32; off>0; off>>=1) acc += __shfl_down(acc, off);
      if (kk==0){
        float v = acc + b2f(outbc[r]);
        size_t oi = ((size_t)(t*64+n))*34 + r;
        if (f32o) ((float*)out)[oi]=v; else ((unsigned short*)out)[oi]=f2b(v);
      }
      if (p < 2 && tid < 64){
        const int r2 = 32+p;
        float a2=0.f;
        const unsigned short* wr2 = outWc + (size_t)r2*512 + tid;
        #pragma unroll
        for (int s=0;s<4;s++) a2 += ctx[s*64+tid]*b2f(wr2[s*64]);
        #pragma unroll
        for (int s=0;s<4;s++) a2 += h2[s*64+tid]*b2f(wr2[256+s*64]);
        #pragma unroll
        for (int off=32; off>0; off>>=1) a2 += __shfl_down(a2, off);
        if (tid==0){
          float v = a2 + b2f(outbc[r2]);
          size_t oi = ((size_t)(t*64+n))*34 + r2;
          if (f32o) ((float*)out)[oi]=v; else ((unsigned short*)out)[oi]=f2b(v);
        }
      }
    }
  }
}

extern "C" void kernel_launch(void* const* d_in, const int* in_sizes, int n_in,
                              void* d_out, int out_size, void* d_ws, size_t ws_size,
                              hipStream_t stream) {
  const void* seqs  = d_in[0];
  const int* seq_lens = (const int*)d_in[1];
  const int* labels   = (const int*)d_in[2];
  const void* emb   = d_in[3];
  const void* inith = d_in[4];
  const void* initc = d_in[5];
  const void* Wih0 = d_in[6];  const void* Whh0 = d_in[7];
  const void* bih0 = d_in[8];  const void* bhh0 = d_in[9];
  const void* Wih1 = d_in[10]; const void* Whh1 = d_in[11];
  const void* bih1 = d_in[12]; const void* bhh1 = d_in[13];
  const void* Wih2 = d_in[14]; const void* Whh2 = d_in[15];
  const void* bih2 = d_in[16]; const void* bhh2 = d_in[17];
  const void* qW0 = d_in[18];  const void* qb0 = d_in[19];
  const void* qW1 = d_in[20];  const void* qb1 = d_in[21];
  const void* kW0 = d_in[22];  const void* kb0 = d_in[23];
  const void* kW1 = d_in[24];  const void* kb1 = d_in[25];
  const void* vW0 = d_in[26];  const void* vb0 = d_in[27];
  const void* vW1 = d_in[28];  const void* vb1 = d_in[29];
  const void* outW = d_in[30]; const void* outb = d_in[31];

  char* ws = (char*)d_ws;
  unsigned short* keyT  = (unsigned short*)(ws);             //  8,388,608 B  [64][64][1024]
  unsigned short* value = (unsigned short*)(ws + 8388608);   // 33,554,432 B  [64][1024][256]
  unsigned short* Wl0   = (unsigned short*)(ws + 41943040);  //  1,048,576 B  [4][512][256]
  unsigned short* Wl1   = (unsigned short*)(ws + 42991616);
  unsigned short* Wl2   = (unsigned short*)(ws + 44040192);
  unsigned short* kW0T  = (unsigned short*)(ws + 45088768);  //    524,288 B (prep-only)
  unsigned short* kW1T  = (unsigned short*)(ws + 45613056);  //     65,536 B (prep-only)
  unsigned short* vW0T  = (unsigned short*)(ws + 45678592);  //    262,144 B (prep-only)
  unsigned short* vW1T  = (unsigned short*)(ws + 45940736);  //    131,072 B (prep-only)
  unsigned short* qW0T  = (unsigned short*)(ws + 46071808);  //    131,072 B
  unsigned short* qW1T  = (unsigned short*)(ws + 46202880);  //     32,768 B
  float*          bsum  = (float*)(ws + 46235648);           //     12,288 B  [3][4][256]
  float*          gep   = (float*)(ws + 46247936);           //    139,264 B  [4][34][256]
  unsigned short* outWc = (unsigned short*)(ws + 46387200);  //     34,816 B
  unsigned short* inithc= (unsigned short*)(ws + 46422016);  //      1,536 B
  unsigned short* initcc= (unsigned short*)(ws + 46423552);  //      1,536 B
  unsigned short* qb0c  = (unsigned short*)(ws + 46425088);  //        512 B
  unsigned short* qb1c  = (unsigned short*)(ws + 46425600);  //        128 B
  unsigned short* outbc = (unsigned short*)(ws + 46425728);  //        128 B
  int*            dflags= (int*)(ws + 46425856);             //         16 B
  // sync region overlaps kW0T..vW0T (all consumed before speller starts):
  int*   syncflags = (int*)(ws + 45088768);                  //      1,024 B  [64][4]
  float* hbuf      = (float*)(ws + 45089792);                //    786,432 B  [64][3072]

  sniff<<<dim3(1), dim3(64), 0, stream>>>(seqs, seq_lens, dflags);
  prep_transpose<<<dim3(8472), dim3(256), 0, stream>>>(
      Wih0,Whh0,Wih1,Whh1,Wih2,Whh2, kW0,kW1,vW0,vW1,qW0,qW1,
      bih0,bhh0,bih1,bhh1,bih2,bhh2,
      outW,inith,initc,qb0,qb1,outb, dflags,
      Wl0,Wl1,Wl2,kW0T,kW1T,vW0T,vW1T,qW0T,qW1T,bsum,
      outWc,inithc,initcc,qb0c,qb1c,outbc);
  prep_ge<<<dim3(34), dim3(256), 0, stream>>>(emb, Wih0, dflags, gep);
  key_mlp<<<dim3(4096), dim3(256), 0, stream>>>(seqs, kW0T, kb0, kW1T, kb1, dflags, keyT);
  value_mlp<<<dim3(4096), dim3(256), 0, stream>>>(seqs, vW0T, vb0, vW1T, vb1, dflags, value);
  zero_sync<<<dim3(1), dim3(256), 0, stream>>>(syncflags);
  hipFuncSetAttribute((const void*)speller, hipFuncAttributeMaxDynamicSharedMemorySize, 131072);
  speller<<<dim3(256), dim3(512), 131072, stream>>>(
      keyT, value, Wl0, Wl1, Wl2, qW0T, qW1T, bsum, gep,
      inithc, initcc, qb0c, qb1c, outWc, outbc, labels, seq_lens, dflags,
      syncflags, hbuf, d_out);
}

// Round 6
// 8238.422 us; speedup vs baseline: 6.9735x; 1.3703x over previous
//
#include <hip/hip_runtime.h>
#include <cstddef>

#define DEV static __device__ __forceinline__
typedef unsigned long long ull;

DEV float b2f(unsigned short u){ unsigned int i=((unsigned int)u)<<16; float f; __builtin_memcpy(&f,&i,4); return f; }
DEV float lo16(unsigned int u){ unsigned int i=u<<16; float f; __builtin_memcpy(&f,&i,4); return f; }
DEV float hi16(unsigned int u){ unsigned int i=u&0xffff0000u; float f; __builtin_memcpy(&f,&i,4); return f; }
DEV unsigned short f2b(float f){ unsigned int i; __builtin_memcpy(&i,&f,4); unsigned int r=(i+0x7fffu+((i>>16)&1u))>>16; return (unsigned short)r; }
DEV float sigf(float x){ return 1.f/(1.f+__expf(-x)); }
DEV float eluf(float x){ return x>0.f ? x : (__expf(x)-1.f); }
DEV float gload(const void* p, long i, int f32){
  return f32 ? ((const float*)p)[i] : b2f(((const unsigned short*)p)[i]);
}
// tagged-word mailbox: {tag<<32 | f32 bits}, relaxed agent atomics (LLC point,
// no L1/L2 invalidation). One MALL trip per word; tag monotone per launch.
DEV ull pk(float f, unsigned tag){ unsigned b; __builtin_memcpy(&b,&f,4); return ((ull)tag<<32)|b; }
DEV float upk(ull u){ unsigned b=(unsigned)u; float f; __builtin_memcpy(&f,&b,4); return f; }
DEV void ast64(ull* p, ull v){ __hip_atomic_store(p, v, __ATOMIC_RELAXED, __HIP_MEMORY_SCOPE_AGENT); }
DEV ull ald64(const ull* p){ return __hip_atomic_load(p, __ATOMIC_RELAXED, __HIP_MEMORY_SCOPE_AGENT); }

// ---------------------------------------------------------------------------
// Sniff input dtypes. flags[0]=1 if floats are f32; flags[1]=1 if ints are i64.
// ---------------------------------------------------------------------------
__global__ __launch_bounds__(64) void sniff(const void* __restrict__ seqs,
                                            const void* __restrict__ seq_lens,
                                            int* __restrict__ flags)
{
  __shared__ int cnt;
  if (threadIdx.x==0) cnt=0;
  __syncthreads();
  const unsigned short* u = (const unsigned short*)seqs;
  int sane=0;
  for (int i=threadIdx.x;i<1024;i+=64){
    int e = (u[i]>>7)&0xFF;
    if (e>=0x70 && e<=0x8F) sane++;
  }
  atomicAdd(&cnt, sane);
  __syncthreads();
  if (threadIdx.x==0){
    flags[0] = (cnt < 820) ? 1 : 0;
    const int* s = (const int*)seq_lens;
    flags[1] = ((s[1]|s[3]|s[5]|s[7])==0) ? 1 : 0;
  }
}

// ---------------------------------------------------------------------------
// Prep: part-sliced bf16 weights (unchanged, verified in r3/r5).
// Wl[l][part][k][gi]: gi in [0,256): type=gi>>6, jj=gi&63,
// g = type*256 + part*64 + jj.  k<256 -> ih (ctx/h_in), k>=256 -> hh.
// ---------------------------------------------------------------------------
__global__ __launch_bounds__(256) void prep_transpose(
    const void* __restrict__ Wih0, const void* __restrict__ Whh0,
    const void* __restrict__ Wih1, const void* __restrict__ Whh1,
    const void* __restrict__ Wih2, const void* __restrict__ Whh2,
    const void* __restrict__ kW0,  const void* __restrict__ kW1,
    const void* __restrict__ vW0,  const void* __restrict__ vW1,
    const void* __restrict__ qW0,  const void* __restrict__ qW1,
    const void* __restrict__ bih0, const void* __restrict__ bhh0,
    const void* __restrict__ bih1, const void* __restrict__ bhh1,
    const void* __restrict__ bih2, const void* __restrict__ bhh2,
    const void* __restrict__ outW, const void* __restrict__ inith,
    const void* __restrict__ initc, const void* __restrict__ qb0,
    const void* __restrict__ qb1,  const void* __restrict__ outb,
    const int* __restrict__ flags,
    unsigned short* __restrict__ Wl0, unsigned short* __restrict__ Wl1,
    unsigned short* __restrict__ Wl2,
    unsigned short* __restrict__ kW0T, unsigned short* __restrict__ kW1T,
    unsigned short* __restrict__ vW0T, unsigned short* __restrict__ vW1T,
    unsigned short* __restrict__ qW0T, unsigned short* __restrict__ qW1T,
    float* __restrict__ bsum,
    unsigned short* __restrict__ outWc, unsigned short* __restrict__ inithc,
    unsigned short* __restrict__ initcc, unsigned short* __restrict__ qb0c,
    unsigned short* __restrict__ qb1c,  unsigned short* __restrict__ outbc)
{
  const int f32 = flags[0];
  int idx = blockIdx.x*256 + threadIdx.x;
  if (idx < 524288){ int r=idx&131071, k=r>>8, gi=r&255;
    int g = ((gi>>6)<<8) + ((idx>>17)<<6) + (gi&63);
    Wl0[idx] = f2b((k<256)? gload(Wih0,(long)g*512+k,f32) : gload(Whh0,(long)g*256+(k-256),f32)); return; }
  idx -= 524288;
  if (idx < 524288){ int r=idx&131071, k=r>>8, gi=r&255;
    int g = ((gi>>6)<<8) + ((idx>>17)<<6) + (gi&63);
    Wl1[idx] = f2b((k<256)? gload(Wih1,(long)g*256+k,f32) : gload(Whh1,(long)g*256+(k-256),f32)); return; }
  idx -= 524288;
  if (idx < 524288){ int r=idx&131071, k=r>>8, gi=r&255;
    int g = ((gi>>6)<<8) + ((idx>>17)<<6) + (gi&63);
    Wl2[idx] = f2b((k<256)? gload(Wih2,(long)g*256+k,f32) : gload(Whh2,(long)g*256+(k-256),f32)); return; }
  idx -= 524288;
  if (idx < 262144){ int k=idx>>9, j=idx&511; kW0T[idx]=f2b(gload(kW0,(long)j*512+k,f32)); return; }
  idx -= 262144;
  if (idx < 32768){ int k=idx>>6, j=idx&63; kW1T[idx]=f2b(gload(kW1,(long)j*512+k,f32)); return; }
  idx -= 32768;
  if (idx < 131072){ int k=idx>>8, j=idx&255; vW0T[idx]=f2b(gload(vW0,(long)j*512+k,f32)); return; }
  idx -= 131072;
  if (idx < 65536){ int k=idx>>8, j=idx&255; vW1T[idx]=f2b(gload(vW1,(long)j*256+k,f32)); return; }
  idx -= 65536;
  if (idx < 65536){ int k=idx>>8, j=idx&255; qW0T[idx]=f2b(gload(qW0,(long)j*256+k,f32)); return; }
  idx -= 65536;
  if (idx < 16384){ int k=idx>>6, j=idx&63; qW1T[idx]=f2b(gload(qW1,(long)j*256+k,f32)); return; }
  idx -= 16384;
  if (idx < 3072){ int l=idx>>10, r=idx&1023, pp=r>>8, gi=r&255;
    int g = ((gi>>6)<<8) + (pp<<6) + (gi&63);
    const void* bi = (l==0)?bih0:((l==1)?bih1:bih2);
    const void* bh = (l==0)?bhh0:((l==1)?bhh1:bhh2);
    bsum[idx] = gload(bi,g,f32)+gload(bh,g,f32); return; }
  idx -= 3072;
  if (idx < 17408){ outWc[idx]=f2b(gload(outW,idx,f32)); return; }
  idx -= 17408;
  if (idx < 768){ inithc[idx]=f2b(gload(inith,idx,f32)); return; }
  idx -= 768;
  if (idx < 768){ initcc[idx]=f2b(gload(initc,idx,f32)); return; }
  idx -= 768;
  if (idx < 256){ qb0c[idx]=f2b(gload(qb0,idx,f32)); return; }
  idx -= 256;
  if (idx < 64){ qb1c[idx]=f2b(gload(qb1,idx,f32)); return; }
  idx -= 64;
  if (idx < 34){ outbc[idx]=f2b(gload(outb,idx,f32)); return; }
}

// gep[part][v][gi] = sum_k emb[v][k] * Wih0[g(part,gi)][256+k]
__global__ __launch_bounds__(256) void prep_ge(
    const void* __restrict__ emb,
    const void* __restrict__ Wih0,
    const int* __restrict__ flags,
    float* __restrict__ gep)
{
  __shared__ float ev[256];
  const int f32 = flags[0];
  const int v = blockIdx.x, tid = threadIdx.x;
  ev[tid] = gload(emb,(long)v*256+tid,f32);
  __syncthreads();
  #pragma unroll
  for (int j=0;j<4;j++){
    const int g = tid*4+j;
    float a = 0.f;
    #pragma unroll 4
    for (int k=0;k<256;k++) a += ev[k]*gload(Wih0,(long)g*512+256+k,f32);
    int pp = (g>>6)&3, gi = ((g>>8)<<6)|(g&63);
    gep[((size_t)pp*34+v)*256+gi] = a;
  }
}

// ---------------------------------------------------------------------------
// key MLP: keyT[n][q][l]  (unchanged)
// ---------------------------------------------------------------------------
__global__ __launch_bounds__(256) void key_mlp(
    const void* __restrict__ seqs,
    const unsigned short* __restrict__ kW0T, const void* __restrict__ kb0,
    const unsigned short* __restrict__ kW1T, const void* __restrict__ kb1,
    const int* __restrict__ flags,
    unsigned short* __restrict__ keyT)
{
  __shared__ float Xt[16*512];
  __shared__ unsigned short Hd[16*512];
  const int f32 = flags[0];
  const int tid = threadIdx.x;
  const int R0 = blockIdx.x*16;
  for (int i=tid;i<8192;i+=256) Xt[i] = gload(seqs,(long)R0*512+i,f32);
  __syncthreads();
  {
    const int j0 = 2*tid;
    float acc0[16], acc1[16];
    #pragma unroll
    for (int r=0;r<16;r++){ acc0[r]=0.f; acc1[r]=0.f; }
    for (int k=0;k<512;k++){
      ushort2 w = *reinterpret_cast<const ushort2*>(kW0T + (size_t)k*512 + j0);
      float w0=b2f(w.x), w1=b2f(w.y);
      #pragma unroll
      for (int r=0;r<16;r++){ float x = Xt[r*512+k]; acc0[r]+=x*w0; acc1[r]+=x*w1; }
    }
    float b0v=gload(kb0,j0,f32), b1v=gload(kb0,j0+1,f32);
    #pragma unroll
    for (int r=0;r<16;r++){
      Hd[r*512+j0]   = f2b(eluf(acc0[r]+b0v));
      Hd[r*512+j0+1] = f2b(eluf(acc1[r]+b1v));
    }
  }
  __syncthreads();
  {
    const int j = tid & 63;
    const int rbase = tid >> 6;
    float acc[4] = {0.f,0.f,0.f,0.f};
    for (int k=0;k<512;k++){
      float w = b2f(kW1T[(size_t)k*64 + j]);
      #pragma unroll
      for (int m=0;m<4;m++) acc[m] += b2f(Hd[(rbase+4*m)*512 + k]) * w;
    }
    float bv = gload(kb1,j,f32);
    #pragma unroll
    for (int m=0;m<4;m++){
      int R = R0 + rbase + 4*m;
      int l = R >> 6, n = R & 63;
      keyT[((size_t)(n*64 + j))*1024 + l] = f2b(acc[m]+bv);
    }
  }
}

// ---------------------------------------------------------------------------
// value MLP: value[n][l][h]  (unchanged)
// ---------------------------------------------------------------------------
__global__ __launch_bounds__(256) void value_mlp(
    const void* __restrict__ seqs,
    const unsigned short* __restrict__ vW0T, const void* __restrict__ vb0,
    const unsigned short* __restrict__ vW1T, const void* __restrict__ vb1,
    const int* __restrict__ flags,
    unsigned short* __restrict__ value)
{
  __shared__ float Xt[16*512];
  __shared__ float Hd[16*256];
  const int f32 = flags[0];
  const int tid = threadIdx.x;
  const int R0 = blockIdx.x*16;
  for (int i=tid;i<8192;i+=256) Xt[i] = gload(seqs,(long)R0*512+i,f32);
  __syncthreads();
  {
    const int j0 = 2*(tid & 127);
    const int rh = tid >> 7;
    float acc0[8], acc1[8];
    #pragma unroll
    for (int r=0;r<8;r++){ acc0[r]=0.f; acc1[r]=0.f; }
    for (int k=0;k<512;k++){
      ushort2 w = *reinterpret_cast<const ushort2*>(vW0T + (size_t)k*256 + j0);
      float w0=b2f(w.x), w1=b2f(w.y);
      #pragma unroll
      for (int r=0;r<8;r++){ float x = Xt[(rh*8+r)*512+k]; acc0[r]+=x*w0; acc1[r]+=x*w1; }
    }
    float b0v=gload(vb0,j0,f32), b1v=gload(vb0,j0+1,f32);
    #pragma unroll
    for (int r=0;r<8;r++){
      Hd[(rh*8+r)*256+j0]   = eluf(acc0[r]+b0v);
      Hd[(rh*8+r)*256+j0+1] = eluf(acc1[r]+b1v);
    }
  }
  __syncthreads();
  {
    const int j = tid;
    float acc[16];
    #pragma unroll
    for (int r=0;r<16;r++) acc[r]=0.f;
    for (int k=0;k<256;k++){
      float w = b2f(vW1T[(size_t)k*256 + j]);
      #pragma unroll
      for (int r=0;r<16;r++) acc[r] += Hd[r*256+k]*w;
    }
    float bv = gload(vb1,j,f32);
    #pragma unroll
    for (int r=0;r<16;r++){
      int R = R0 + r; int l = R>>6, n = R&63;
      value[((size_t)n*1024 + l)*256 + j] = f2b(acc[r]+bv);
    }
  }
}

__global__ __launch_bounds__(256) void zero_hbuf(ull* __restrict__ f){
  int i = blockIdx.x*256 + threadIdx.x;
  if (i < 115200) f[i] = 0;   // tag 0 matches no round (tags start at 1)
}

// ---------------------------------------------------------------------------
// Decode: 256 blocks x 512 threads, 1 block/CU. Block bid = n*4+p so XCD
// (bid%8 round-robin) hosts a single part value -> per-XCD L2 footprint
// ~2 MB (weights/keyT resident). Cross-part exchange: self-tagged 64-bit
// relaxed agent atomics (one MALL trip/word, no flag indirection).
// Mailbox per n (ull): H0[256] H1[256] H2[256] PCTX[4][256] STAT[4][2].
// ---------------------------------------------------------------------------
__global__ __launch_bounds__(512, 1) void speller(
    const unsigned short* __restrict__ keyT,
    const unsigned short* __restrict__ value,
    const unsigned short* __restrict__ Wl0,
    const unsigned short* __restrict__ Wl1,
    const unsigned short* __restrict__ Wl2,
    const unsigned short* __restrict__ qW0T,
    const unsigned short* __restrict__ qW1T,
    const float* __restrict__ bsum_p,
    const float* __restrict__ gep,
    const unsigned short* __restrict__ inithc,
    const unsigned short* __restrict__ initcc,
    const unsigned short* __restrict__ qb0c,
    const unsigned short* __restrict__ qb1c,
    const unsigned short* __restrict__ outWc,
    const unsigned short* __restrict__ outbc,
    const int* __restrict__ labels,
    const int* __restrict__ seq_lens,
    const int* __restrict__ dflags,
    ull* __restrict__ hbw,
    void* __restrict__ out)
{
  extern __shared__ char smem_dyn[];
  unsigned short* vlds = (unsigned short*)smem_dyn;   // [256 l][256 h] quarter, 128 KB

  __shared__ float sacc[4096];
  __shared__ float inc[512];
  __shared__ float garr[256];
  __shared__ float h0[256], h1[256], h2[256], ctx[256];
  __shared__ float cloc[3][64];
  __shared__ float hsl[3][64];
  __shared__ float xq[256];
  __shared__ float qv[64];
  __shared__ float sarr[256], earr[256];
  __shared__ float red[128];
  __shared__ float wf[4];
  __shared__ float pcl[256];
  __shared__ float statl[8];

  const int tid = threadIdx.x;
  const int n = blockIdx.x >> 2;     // bid = n*4 + p
  const int p = blockIdx.x & 3;
  const int f32o = dflags[0];
  const int i64 = dflags[1];
  const int slen = i64 ? seq_lens[2*n] : seq_lens[n];

  ull* mb   = hbw + (size_t)n*1800;
  ull* H0w  = mb;            // [256]
  ull* H1w  = mb + 256;      // [256]
  ull* H2w  = mb + 512;      // [256]
  ull* PCw  = mb + 768;      // [4][256]
  ull* STw  = mb + 1792;     // [4][2]

  // preload value quarter into LDS (once)
  {
    const uint4* src = (const uint4*)(value + ((size_t)n*1024 + p*256)*256);
    uint4* dst = (uint4*)vlds;
    for (int i=tid;i<16384;i+=512) dst[i] = src[i];
  }
  if (tid < 256){ h0[tid]=b2f(inithc[tid]); h1[tid]=b2f(inithc[256+tid]); h2[tid]=b2f(inithc[512+tid]); }
  if (tid < 64){
    cloc[0][tid]=b2f(initcc[p*64+tid]);
    cloc[1][tid]=b2f(initcc[256+p*64+tid]);
    cloc[2][tid]=b2f(initcc[512+p*64+tid]);
  }
  __syncthreads();

  // LSTM gate slice from inc[512]; own h slice -> LDS hsl[layer] + tagged mailbox.
  auto lstm = [&](const unsigned short* W, const float* bs, const float* ger,
                  int layer, ull* Hw, unsigned tag){
    const int go8 = tid & 31, ks = tid >> 5;
    const unsigned short* wp = W + (size_t)p*131072 + (size_t)ks*32*256 + go8*8;
    const float* xin = inc + ks*32;
    float a0=0.f,a1=0.f,a2=0.f,a3=0.f,a4=0.f,a5=0.f,a6=0.f,a7=0.f;
    #pragma unroll 16
    for (int k=0;k<32;k++){
      float x = xin[k];
      uint4 w = *reinterpret_cast<const uint4*>(wp + (size_t)k*256);
      a0 += x*lo16(w.x); a1 += x*hi16(w.x);
      a2 += x*lo16(w.y); a3 += x*hi16(w.y);
      a4 += x*lo16(w.z); a5 += x*hi16(w.z);
      a6 += x*lo16(w.w); a7 += x*hi16(w.w);
    }
    float* sb = sacc + ks*256 + go8*8;
    sb[0]=a0; sb[1]=a1; sb[2]=a2; sb[3]=a3; sb[4]=a4; sb[5]=a5; sb[6]=a6; sb[7]=a7;
    __syncthreads();
    if (tid < 256){
      float s = bs[tid] + (ger ? ger[tid] : 0.f);
      #pragma unroll
      for (int u=0;u<16;u++) s += sacc[u*256+tid];
      garr[tid] = s;
    }
    __syncthreads();
    if (tid < 64){
      float gi=garr[tid], gf=garr[64+tid], gg=garr[128+tid], go=garr[192+tid];
      float cc = sigf(gf)*cloc[layer][tid] + sigf(gi)*tanhf(gg);
      float hh = sigf(go)*tanhf(cc);
      cloc[layer][tid]=cc;
      hsl[layer][tid]=hh;
      ast64(Hw + p*64 + tid, pk(hh, tag));
    }
    // no trailing barrier; gather opens with one (covers hsl write)
  };

  // gather full h vector: own slice from LDS, 3 remote slices by tag-poll.
  auto gather_h = [&](const ull* Hw, int layer, unsigned tag, float* hdst){
    __syncthreads();
    if (tid < 256){
      int sp = tid >> 6; float v;
      if (sp == p) v = hsl[layer][tid & 63];
      else { const ull* w = Hw + tid; ull u = ald64(w);
             while ((unsigned)(u>>32) != tag) u = ald64(w);
             v = upk(u); }
      hdst[tid] = v;
    }
    __syncthreads();
  };

  // attention: replicated q-MLP from full h2 (LDS), own l-quarter scores +
  // softmax partials + partial ctx -> tagged mailbox; exact assembly.
  auto attn = [&](unsigned tag){
    { // xq replicated: col j, two k-halves of 128
      const int j = tid & 255, kh = tid >> 8;
      const unsigned short* qp = qW0T + (size_t)(kh*128)*256 + j;
      float a = 0.f;
      #pragma unroll 8
      for (int k=0;k<128;k++) a += h2[kh*128+k]*b2f(qp[(size_t)k*256]);
      sacc[kh*256 + j] = a;
    }
    __syncthreads();
    if (tid < 256) xq[tid] = eluf(sacc[tid]+sacc[256+tid] + b2f(qb0c[tid]));
    __syncthreads();
    { // qv: 64 cols x 8 k-strips of 32
      const int qc = tid & 63, k8 = tid >> 6;
      float a = 0.f;
      const unsigned short* qp = qW1T + qc;
      #pragma unroll 8
      for (int k=0;k<32;k++){ int kk = k8*32+k; a += xq[kk]*b2f(qp[(size_t)kk*64]); }
      sacc[k8*64+qc] = a;
    }
    __syncthreads();
    if (tid < 64){
      float s=0.f;
      #pragma unroll
      for (int u=0;u<8;u++) s += sacc[u*64+tid];
      qv[tid] = s + b2f(qb1c[tid]);
    }
    __syncthreads();
    { // scores own l-quarter: l-pairs x 4 q-chunks of 16
      const int lp = tid & 127, qh = tid >> 7;
      float a0=0.f,a1=0.f;
      const unsigned short* kp = keyT + (size_t)n*65536 + (size_t)qh*16*1024 + p*256 + 2*lp;
      #pragma unroll 8
      for (int q=0;q<16;q++){
        ushort2 w = *reinterpret_cast<const ushort2*>(kp + (size_t)q*1024);
        float qq = qv[qh*16+q];
        a0 += qq*b2f(w.x); a1 += qq*b2f(w.y);
      }
      sacc[qh*256+2*lp]=a0; sacc[qh*256+2*lp+1]=a1;
    }
    __syncthreads();
    if (tid < 256){
      float s = sacc[tid]+sacc[256+tid]+sacc[512+tid]+sacc[768+tid];
      sarr[tid] = (p*256+tid < slen) ? s : -1e30f;
    }
    __syncthreads();
    if (tid < 128) red[tid] = fmaxf(sarr[tid], sarr[tid+128]);
    __syncthreads();
    for (int s=64;s>0;s>>=1){ if (tid<s) red[tid]=fmaxf(red[tid],red[tid+s]); __syncthreads(); }
    const float pmax = red[0];
    __syncthreads();
    if (tid < 256) earr[tid] = (p*256+tid < slen) ? __expf(sarr[tid]-pmax) : 0.f;
    __syncthreads();
    if (tid < 128) red[tid] = earr[tid]+earr[tid+128];
    __syncthreads();
    for (int s=64;s>0;s>>=1){ if (tid<s) red[tid]+=red[tid+s]; __syncthreads(); }
    const float psum = red[0];
    { // partial ctx from LDS value: h-pairs x 4 l-chunks of 64
      const int hp = tid & 127, lq = tid >> 7;
      float a0=0.f,a1=0.f;
      const unsigned short* vp = vlds + (size_t)(lq*64)*256 + 2*hp;
      #pragma unroll 8
      for (int l=0;l<64;l++){
        ushort2 w = *reinterpret_cast<const ushort2*>(vp + (size_t)l*256);
        float e = earr[lq*64+l];
        a0 += e*b2f(w.x); a1 += e*b2f(w.y);
      }
      sacc[lq*256+2*hp]=a0; sacc[lq*256+2*hp+1]=a1;
    }
    __syncthreads();
    if (tid < 256){
      float v = sacc[tid]+sacc[256+tid]+sacc[512+tid]+sacc[768+tid];
      pcl[tid] = v;
      ast64(PCw + p*256 + tid, pk(v, tag));
    }
    if (tid == 0){ ast64(STw + p*2, pk(pmax, tag)); ast64(STw + p*2 + 1, pk(psum, tag)); }
    // stats gather (all 4 parts): own from registers, remote by poll
    if (tid < 8){
      int q = tid >> 1, ix = tid & 1; float v;
      if (q == p) v = ix ? psum : pmax;
      else { const ull* w = STw + q*2 + ix; ull u = ald64(w);
             while ((unsigned)(u>>32) != tag) u = ald64(w);
             v = upk(u); }
      statl[tid] = v;
    }
    __syncthreads();
    if (tid == 0){
      float m0=statl[0], s0=statl[1], m1=statl[2], s1=statl[3];
      float m2=statl[4], s2=statl[5], m3=statl[6], s3=statl[7];
      float M = fmaxf(fmaxf(m0,m1),fmaxf(m2,m3));
      float w0=__expf(m0-M), w1=__expf(m1-M), w2=__expf(m2-M), w3=__expf(m3-M);
      float inv = 1.f/(s0*w0+s1*w1+s2*w2+s3*w3);
      wf[0]=w0*inv; wf[1]=w1*inv; wf[2]=w2*inv; wf[3]=w3*inv;
    }
    __syncthreads();
    if (tid < 256){
      float acc = pcl[tid]*wf[p];
      #pragma unroll
      for (int q=0;q<4;q++){
        if (q == p) continue;
        const ull* w = PCw + q*256 + tid; ull u = ald64(w);
        while ((unsigned)(u>>32) != tag) u = ald64(w);
        acc += upk(u)*wf[q];
      }
      ctx[tid] = acc;
    }
    __syncthreads();
  };

  attn(1);   // initial prev_ctx from inith[2] (h2 local, no gather needed)

  for (int t=0;t<256;t++){
    const unsigned tb = 4*(unsigned)t;
    const int lab = i64 ? labels[2*(t*64+n)] : labels[t*64+n];
    // stage A: L0 uses {ctx, h0_prev}
    if (tid < 256){ inc[tid]=ctx[tid]; inc[256+tid]=h0[tid]; }
    __syncthreads();
    lstm(Wl0, bsum_p + p*256, gep + ((size_t)p*34+lab)*256, 0, H0w, tb+2);
    gather_h(H0w, 0, tb+2, h0);
    // stage B: L1 uses {h0_new, h1_prev}
    if (tid < 256){ inc[tid]=h0[tid]; inc[256+tid]=h1[tid]; }
    __syncthreads();
    lstm(Wl1, bsum_p + 1024 + p*256, nullptr, 1, H1w, tb+3);
    gather_h(H1w, 1, tb+3, h1);
    // stage C: L2 uses {h1_new, h2_prev}
    if (tid < 256){ inc[tid]=h1[tid]; inc[256+tid]=h2[tid]; }
    __syncthreads();
    lstm(Wl2, bsum_p + 2048 + p*256, nullptr, 2, H2w, tb+4);
    gather_h(H2w, 2, tb+4, h2);
    // stage D: attention
    attn(tb+5);
    // out projection: rows r = 4*ri + p (+ rows 32,33 on parts 0,1)
    {
      const int ri = tid >> 6, kk = tid & 63;
      const int r = 4*ri + p;
      float acc = 0.f;
      const unsigned short* wr = outWc + (size_t)r*512 + kk;
      #pragma unroll
      for (int s=0;s<4;s++) acc += ctx[s*64+kk]*b2f(wr[s*64]);
      #pragma unroll
      for (int s=0;s<4;s++) acc += h2[s*64+kk]*b2f(wr[256+s*64]);
      #pragma unroll
      for (int off=32; off>0; off>>=1) acc += __shfl_down(acc, off);
      if (kk==0){
        float v = acc + b2f(outbc[r]);
        size_t oi = ((size_t)(t*64+n))*34 + r;
        if (f32o) ((float*)out)[oi]=v; else ((unsigned short*)out)[oi]=f2b(v);
      }
      if (p < 2 && tid < 64){
        const int r2 = 32+p;
        float a2=0.f;
        const unsigned short* wr2 = outWc + (size_t)r2*512 + tid;
        #pragma unroll
        for (int s=0;s<4;s++) a2 += ctx[s*64+tid]*b2f(wr2[s*64]);
        #pragma unroll
        for (int s=0;s<4;s++) a2 += h2[s*64+tid]*b2f(wr2[256+s*64]);
        #pragma unroll
        for (int off=32; off>0; off>>=1) a2 += __shfl_down(a2, off);
        if (tid==0){
          float v = a2 + b2f(outbc[r2]);
          size_t oi = ((size_t)(t*64+n))*34 + r2;
          if (f32o) ((float*)out)[oi]=v; else ((unsigned short*)out)[oi]=f2b(v);
        }
      }
    }
  }
}

extern "C" void kernel_launch(void* const* d_in, const int* in_sizes, int n_in,
                              void* d_out, int out_size, void* d_ws, size_t ws_size,
                              hipStream_t stream) {
  const void* seqs  = d_in[0];
  const int* seq_lens = (const int*)d_in[1];
  const int* labels   = (const int*)d_in[2];
  const void* emb   = d_in[3];
  const void* inith = d_in[4];
  const void* initc = d_in[5];
  const void* Wih0 = d_in[6];  const void* Whh0 = d_in[7];
  const void* bih0 = d_in[8];  const void* bhh0 = d_in[9];
  const void* Wih1 = d_in[10]; const void* Whh1 = d_in[11];
  const void* bih1 = d_in[12]; const void* bhh1 = d_in[13];
  const void* Wih2 = d_in[14]; const void* Whh2 = d_in[15];
  const void* bih2 = d_in[16]; const void* bhh2 = d_in[17];
  const void* qW0 = d_in[18];  const void* qb0 = d_in[19];
  const void* qW1 = d_in[20];  const void* qb1 = d_in[21];
  const void* kW0 = d_in[22];  const void* kb0 = d_in[23];
  const void* kW1 = d_in[24];  const void* kb1 = d_in[25];
  const void* vW0 = d_in[26];  const void* vb0 = d_in[27];
  const void* vW1 = d_in[28];  const void* vb1 = d_in[29];
  const void* outW = d_in[30]; const void* outb = d_in[31];

  char* ws = (char*)d_ws;
  unsigned short* keyT  = (unsigned short*)(ws);             //  8,388,608 B  [64][64][1024]
  unsigned short* value = (unsigned short*)(ws + 8388608);   // 33,554,432 B  [64][1024][256]
  unsigned short* Wl0   = (unsigned short*)(ws + 41943040);  //  1,048,576 B  [4][512][256]
  unsigned short* Wl1   = (unsigned short*)(ws + 42991616);
  unsigned short* Wl2   = (unsigned short*)(ws + 44040192);
  unsigned short* kW0T  = (unsigned short*)(ws + 45088768);  //    524,288 B (prep-only)
  unsigned short* kW1T  = (unsigned short*)(ws + 45613056);  //     65,536 B (prep-only)
  unsigned short* vW0T  = (unsigned short*)(ws + 45678592);  //    262,144 B (prep-only)
  unsigned short* vW1T  = (unsigned short*)(ws + 45940736);  //    131,072 B (prep-only)
  unsigned short* qW0T  = (unsigned short*)(ws + 46071808);  //    131,072 B
  unsigned short* qW1T  = (unsigned short*)(ws + 46202880);  //     32,768 B
  float*          bsum  = (float*)(ws + 46235648);           //     12,288 B  [3][4][256]
  float*          gep   = (float*)(ws + 46247936);           //    139,264 B  [4][34][256]
  unsigned short* outWc = (unsigned short*)(ws + 46387200);  //     34,816 B
  unsigned short* inithc= (unsigned short*)(ws + 46422016);  //      1,536 B
  unsigned short* initcc= (unsigned short*)(ws + 46423552);  //      1,536 B
  unsigned short* qb0c  = (unsigned short*)(ws + 46425088);  //        512 B
  unsigned short* qb1c  = (unsigned short*)(ws + 46425600);  //        128 B
  unsigned short* outbc = (unsigned short*)(ws + 46425728);  //        128 B
  int*            dflags= (int*)(ws + 46425856);             //         16 B
  // tagged mailbox overlaps kW0T..vW1T (all consumed before speller starts):
  ull* hbw = (ull*)(ws + 45088768);                          //    921,600 B  [64][1800] ull

  sniff<<<dim3(1), dim3(64), 0, stream>>>(seqs, seq_lens, dflags);
  prep_transpose<<<dim3(8472), dim3(256), 0, stream>>>(
      Wih0,Whh0,Wih1,Whh1,Wih2,Whh2, kW0,kW1,vW0,vW1,qW0,qW1,
      bih0,bhh0,bih1,bhh1,bih2,bhh2,
      outW,inith,initc,qb0,qb1,outb, dflags,
      Wl0,Wl1,Wl2,kW0T,kW1T,vW0T,vW1T,qW0T,qW1T,bsum,
      outWc,inithc,initcc,qb0c,qb1c,outbc);
  prep_ge<<<dim3(34), dim3(256), 0, stream>>>(emb, Wih0, dflags, gep);
  key_mlp<<<dim3(4096), dim3(256), 0, stream>>>(seqs, kW0T, kb0, kW1T, kb1, dflags, keyT);
  value_mlp<<<dim3(4096), dim3(256), 0, stream>>>(seqs, vW0T, vb0, vW1T, vb1, dflags, value);
  zero_hbuf<<<dim3(450), dim3(256), 0, stream>>>(hbw);
  hipFuncSetAttribute((const void*)speller, hipFuncAttributeMaxDynamicSharedMemorySize, 131072);
  speller<<<dim3(256), dim3(512), 131072, stream>>>(
      keyT, value, Wl0, Wl1, Wl2, qW0T, qW1T, bsum, gep,
      inithc, initcc, qb0c, qb1c, outWc, outbc, labels, seq_lens, dflags,
      hbw, d_out);
}